// Round 1
// baseline (2717.260 us; speedup 1.0000x reference)
//
#include <hip/hip_runtime.h>
#include <math.h>

#define N_NODES 524288
#define N_EDGES 16777216
#define B_ROWS  8192      // N_NODES / 64
#define H1      1024
#define DOUT    128

__device__ __forceinline__ float sigmoid_f(float v) {
    return 1.0f / (1.0f + __expf(-v));
}
__device__ __forceinline__ float softplus_f(float v) {
    // stable: max(v,0) + log1p(exp(-|v|))
    return fmaxf(v, 0.0f) + log1pf(__expf(-fabsf(v)));
}

// ---------------- edge pass 1: gated message + degree -----------------------
__global__ __launch_bounds__(256) void edge_pass1(
    const int* __restrict__ ei, const float* __restrict__ ea,
    const float* __restrict__ x,
    const float* __restrict__ cg_wf, const float* __restrict__ cg_bf,
    const float* __restrict__ cg_ws, const float* __restrict__ cg_bs,
    float* __restrict__ msg_sum, float* __restrict__ deg)
{
    const float wf0 = cg_wf[0], wf1 = cg_wf[1], wf2 = cg_wf[2], bf = cg_bf[0];
    const float s0 = cg_ws[0], s1 = cg_ws[1], s2 = cg_ws[2], bs = cg_bs[0];
    const int t = blockIdx.x * 256 + threadIdx.x;        // N_EDGES/4 threads
    const int4 src4 = ((const int4*)ei)[t];
    const int4 dst4 = ((const int4*)(ei + N_EDGES))[t];
    const float4 w4 = ((const float4*)ea)[t];
    const int* sp = (const int*)&src4;
    const int* dp = (const int*)&dst4;
    const float* wp = (const float*)&w4;
#pragma unroll
    for (int q = 0; q < 4; ++q) {
        const int src = sp[q], dst = dp[q];
        const float w = wp[q];
        const float xs = x[src], xd = x[dst];
        const float f = fmaf(wf0, xd, fmaf(wf1, xs, fmaf(wf2, w, bf)));
        const float s = fmaf(s0, xd, fmaf(s1, xs, fmaf(s2, w, bs)));
        const float msg = sigmoid_f(f) * softplus_f(s);
        unsafeAtomicAdd(&msg_sum[dst], msg);
        unsafeAtomicAdd(&deg[dst], w);
    }
}

// ---------------- node mid: h=relu(x+msg); dinv; a = dinv*h*gcn_w -----------
__global__ __launch_bounds__(256) void node_mid(
    const float* __restrict__ x, const float* __restrict__ msg_sum,
    float* __restrict__ deg_dinv, float* __restrict__ a,
    const float* __restrict__ gcn_w)
{
    const int i = blockIdx.x * 256 + threadIdx.x;
    const float gw = gcn_w[0];
    const float h = fmaxf(x[i] + msg_sum[i], 0.0f);
    const float d = deg_dinv[i];
    const float dinv = (d > 0.0f) ? (1.0f / sqrtf(fmaxf(d, 1e-12f))) : 0.0f;
    deg_dinv[i] = dinv;                 // overwrite deg with dinv
    a[i] = dinv * h * gw;
}

// ---------------- edge pass 2: s[dst] += a[src]*w ---------------------------
__global__ __launch_bounds__(256) void edge_pass2(
    const int* __restrict__ ei, const float* __restrict__ ea,
    const float* __restrict__ a, float* __restrict__ s)
{
    const int t = blockIdx.x * 256 + threadIdx.x;
    const int4 src4 = ((const int4*)ei)[t];
    const int4 dst4 = ((const int4*)(ei + N_EDGES))[t];
    const float4 w4 = ((const float4*)ea)[t];
    const int* sp = (const int*)&src4;
    const int* dp = (const int*)&dst4;
    const float* wp = (const float*)&w4;
#pragma unroll
    for (int q = 0; q < 4; ++q) {
        unsafeAtomicAdd(&s[dp[q]], a[sp[q]] * wp[q]);
    }
}

// ---------------- node fin: hfin = relu(dinv*s + gcn_b) ---------------------
__global__ __launch_bounds__(256) void node_fin(
    const float* __restrict__ dinv, const float* __restrict__ s,
    const float* __restrict__ gcn_b, float* __restrict__ hfin)
{
    const int i = blockIdx.x * 256 + threadIdx.x;
    hfin[i] = fmaxf(fmaf(dinv[i], s[i], gcn_b[0]), 0.0f);
}

// ---------------- fold BN into l3 weights/bias ------------------------------
__global__ __launch_bounds__(256) void fold_bn(
    const float* __restrict__ l3_w, const float* __restrict__ l3_b,
    const float* __restrict__ g, const float* __restrict__ be,
    float* __restrict__ w3f, float* __restrict__ b3f)
{
    const int idx = blockIdx.x * 256 + threadIdx.x;     // 65536
    const int j = idx >> 6, k = idx & 63;
    const float invs = 1.0f / sqrtf(1.0f + 1e-5f);
    const float sc = g[j] * invs;
    w3f[idx] = l3_w[idx] * sc;
    if (k == 0) b3f[j] = fmaf(l3_b[j], sc, be[j]);
}

// ---------------- GEMM1: (8192x64)@(1024x64)^T + bias, relu -----------------
__global__ __launch_bounds__(256) void gemm1(
    const float* __restrict__ A, const float* __restrict__ W,
    const float* __restrict__ bias, float* __restrict__ C)
{
    __shared__ float As[64][68];   // [k][i], pad 4
    __shared__ float Ws[64][68];   // [k][j]
    const int bj = blockIdx.x, bi = blockIdx.y;
    const int t = threadIdx.x;
#pragma unroll
    for (int q2 = 0; q2 < 4; ++q2) {
        const int idx = t + 256 * q2;
        const int r = idx >> 4, c = idx & 15;
        const float4 va = *(const float4*)(A + (size_t)(bi * 64 + r) * 64 + c * 4);
        const float4 vw = *(const float4*)(W + (size_t)(bj * 64 + r) * 64 + c * 4);
        As[c*4+0][r] = va.x; As[c*4+1][r] = va.y; As[c*4+2][r] = va.z; As[c*4+3][r] = va.w;
        Ws[c*4+0][r] = vw.x; Ws[c*4+1][r] = vw.y; Ws[c*4+2][r] = vw.z; Ws[c*4+3][r] = vw.w;
    }
    __syncthreads();
    const int tx = t & 15, ty = t >> 4;
    const int i0 = ty * 4, j0 = tx * 4;
    float acc[4][4] = {};
#pragma unroll 16
    for (int k = 0; k < 64; ++k) {
        const float4 av = *(const float4*)&As[k][i0];
        const float4 wv = *(const float4*)&Ws[k][j0];
        const float* ap = (const float*)&av;
        const float* wp = (const float*)&wv;
#pragma unroll
        for (int ii = 0; ii < 4; ++ii)
#pragma unroll
            for (int jj = 0; jj < 4; ++jj)
                acc[ii][jj] = fmaf(ap[ii], wp[jj], acc[ii][jj]);
    }
    const int gj = bj * 64 + j0;
    const float4 bv = *(const float4*)(bias + gj);
#pragma unroll
    for (int ii = 0; ii < 4; ++ii) {
        const int gi = bi * 64 + i0 + ii;
        float4 o;
        o.x = fmaxf(acc[ii][0] + bv.x, 0.0f);
        o.y = fmaxf(acc[ii][1] + bv.y, 0.0f);
        o.z = fmaxf(acc[ii][2] + bv.z, 0.0f);
        o.w = fmaxf(acc[ii][3] + bv.w, 0.0f);
        *(float4*)(C + (size_t)gi * H1 + gj) = o;
    }
}

// ---------------- GEMM2: (8192x1024)@(128x1024)^T + bias, relu --------------
__global__ __launch_bounds__(256) void gemm2(
    const float* __restrict__ H, const float* __restrict__ W,
    const float* __restrict__ bias, float* __restrict__ O)
{
    __shared__ float Hs[64][36];    // [k][i], 32 + 4 pad
    __shared__ float Ws[64][132];   // [k][j], 128 + 4 pad
    const int bi = blockIdx.x;      // 256 blocks, 32 rows each
    const int t = threadIdx.x;
    const int tx = t & 31, ty = t >> 5;
    const int i0 = ty * 4, j0 = tx * 4;
    float acc[4][4] = {};
    for (int kc = 0; kc < H1; kc += 64) {
#pragma unroll
        for (int q2 = 0; q2 < 2; ++q2) {
            const int idx = t + 256 * q2;
            const int r = idx >> 4, c = idx & 15;
            const float4 v = *(const float4*)(H + (size_t)(bi * 32 + r) * H1 + kc + c * 4);
            Hs[c*4+0][r] = v.x; Hs[c*4+1][r] = v.y; Hs[c*4+2][r] = v.z; Hs[c*4+3][r] = v.w;
        }
#pragma unroll
        for (int q2 = 0; q2 < 8; ++q2) {
            const int idx = t + 256 * q2;
            const int r = idx >> 4, c = idx & 15;
            const float4 v = *(const float4*)(W + (size_t)r * H1 + kc + c * 4);
            Ws[c*4+0][r] = v.x; Ws[c*4+1][r] = v.y; Ws[c*4+2][r] = v.z; Ws[c*4+3][r] = v.w;
        }
        __syncthreads();
#pragma unroll 16
        for (int k = 0; k < 64; ++k) {
            const float4 hv = *(const float4*)&Hs[k][i0];
            const float4 wv = *(const float4*)&Ws[k][j0];
            const float* hp = (const float*)&hv;
            const float* wp = (const float*)&wv;
#pragma unroll
            for (int ii = 0; ii < 4; ++ii)
#pragma unroll
                for (int jj = 0; jj < 4; ++jj)
                    acc[ii][jj] = fmaf(hp[ii], wp[jj], acc[ii][jj]);
        }
        __syncthreads();
    }
    const float4 bv = *(const float4*)(bias + j0);
#pragma unroll
    for (int ii = 0; ii < 4; ++ii) {
        const int gi = bi * 32 + i0 + ii;
        float4 o;
        o.x = fmaxf(acc[ii][0] + bv.x, 0.0f);
        o.y = fmaxf(acc[ii][1] + bv.y, 0.0f);
        o.z = fmaxf(acc[ii][2] + bv.z, 0.0f);
        o.w = fmaxf(acc[ii][3] + bv.w, 0.0f);
        *(float4*)(O + (size_t)gi * DOUT + j0) = o;
    }
}

extern "C" void kernel_launch(void* const* d_in, const int* in_sizes, int n_in,
                              void* d_out, int out_size, void* d_ws, size_t ws_size,
                              hipStream_t stream) {
    const float* x     = (const float*)d_in[0];
    const float* ea    = (const float*)d_in[1];
    const float* cg_wf = (const float*)d_in[2];
    const float* cg_bf = (const float*)d_in[3];
    const float* cg_ws = (const float*)d_in[4];
    const float* cg_bs = (const float*)d_in[5];
    const float* gcn_w = (const float*)d_in[6];
    const float* gcn_b = (const float*)d_in[7];
    const float* l3_w  = (const float*)d_in[8];
    const float* l3_b  = (const float*)d_in[9];
    const float* bn_g  = (const float*)d_in[10];
    const float* bn_b  = (const float*)d_in[11];
    const float* l4_w  = (const float*)d_in[12];
    const float* l4_b  = (const float*)d_in[13];
    const int*   ei    = (const int*)d_in[14];
    float* out = (float*)d_out;

    char* ws = (char*)d_ws;
    float* buf_msg  = (float*)(ws + 0);                 // N floats; reused as s
    float* buf_deg  = (float*)(ws + (size_t)2097152);   // N floats; becomes dinv
    float* buf_a    = (float*)(ws + (size_t)4194304);   // N floats
    float* buf_hfin = (float*)(ws + (size_t)6291456);   // N floats
    float* buf_h3   = (float*)(ws + (size_t)8388608);   // 8192*1024 floats
    float* buf_w3   = (float*)(ws + (size_t)41943040);  // 1024*64 floats
    float* buf_b3   = (float*)(ws + (size_t)42205184);  // 1024 floats

    hipMemsetAsync(buf_msg, 0, (size_t)N_NODES * 4, stream);
    hipMemsetAsync(buf_deg, 0, (size_t)N_NODES * 4, stream);

    fold_bn<<<256, 256, 0, stream>>>(l3_w, l3_b, bn_g, bn_b, buf_w3, buf_b3);

    edge_pass1<<<N_EDGES / 4 / 256, 256, 0, stream>>>(
        ei, ea, x, cg_wf, cg_bf, cg_ws, cg_bs, buf_msg, buf_deg);

    node_mid<<<N_NODES / 256, 256, 0, stream>>>(x, buf_msg, buf_deg, buf_a, gcn_w);

    hipMemsetAsync(buf_msg, 0, (size_t)N_NODES * 4, stream);

    edge_pass2<<<N_EDGES / 4 / 256, 256, 0, stream>>>(ei, ea, buf_a, buf_msg);

    node_fin<<<N_NODES / 256, 256, 0, stream>>>(buf_deg, buf_msg, gcn_b, buf_hfin);

    gemm1<<<dim3(16, 128), 256, 0, stream>>>(buf_hfin, buf_w3, buf_b3, buf_h3);
    gemm2<<<256, 256, 0, stream>>>(buf_h3, l4_w, l4_b, out);
}

// Round 2
// 950.662 us; speedup vs baseline: 2.8583x; 2.8583x over previous
//
#include <hip/hip_runtime.h>
#include <math.h>

#define N_NODES 524288
#define N_EDGES 16777216
#define H1      1024
#define DOUT    128

// bucketed-scatter parameters
#define NB        64               // buckets
#define BSH       13               // log2(nodes per bucket)
#define NODES_PB  8192             // nodes per bucket
#define NCHUNK    1024             // edge chunks (one workgroup each)
#define EPC       (N_EDGES / NCHUNK)   // 16384 edges per chunk
#define CAP       278528           // per-bucket record capacity (262144 avg + 16K slack)
#define PWG       8                // workgroups per bucket in accumulate phases

__device__ __forceinline__ float sigmoid_f(float v) {
    return 1.0f / (1.0f + __expf(-v));
}
__device__ __forceinline__ float softplus_f(float v) {
    return fmaxf(v, 0.0f) + log1pf(__expf(-fabsf(v)));
}

// ============================ bucketed path =================================

// ---- A0: per-chunk histogram of dst buckets --------------------------------
__global__ __launch_bounds__(256) void a0_count(
    const int* __restrict__ ei, int* __restrict__ chunk_cnt)
{
    __shared__ int h[NB];
    const int c = blockIdx.x;
    for (int i = threadIdx.x; i < NB; i += 256) h[i] = 0;
    __syncthreads();
    const int4* d4 = (const int4*)(ei + N_EDGES) + (size_t)c * (EPC / 4);
    for (int i = threadIdx.x; i < EPC / 4; i += 256) {
        const int4 v = d4[i];
        atomicAdd(&h[v.x >> BSH], 1);
        atomicAdd(&h[v.y >> BSH], 1);
        atomicAdd(&h[v.z >> BSH], 1);
        atomicAdd(&h[v.w >> BSH], 1);
    }
    __syncthreads();
    for (int i = threadIdx.x; i < NB; i += 256)
        chunk_cnt[i * NCHUNK + c] = h[i];      // bucket-major
}

// ---- A-scan: per-bucket exclusive prefix over 1024 chunk counts ------------
__global__ __launch_bounds__(256) void a_scan(
    const int* __restrict__ cc, int* __restrict__ cb, int* __restrict__ btot)
{
    const int b = blockIdx.x;
    const int t = threadIdx.x;
    __shared__ int buf[NCHUNK];
    __shared__ int ts[256];
    for (int i = t; i < NCHUNK; i += 256) buf[i] = cc[b * NCHUNK + i];
    __syncthreads();
    int loc[4];
    int s = 0;
#pragma unroll
    for (int j = 0; j < 4; ++j) { loc[j] = s; s += buf[t * 4 + j]; }
    ts[t] = s;
    __syncthreads();
    for (int off = 1; off < 256; off <<= 1) {
        const int v = (t >= off) ? ts[t - off] : 0;
        __syncthreads();
        ts[t] += v;
        __syncthreads();
    }
    const int excl = (t == 0) ? 0 : ts[t - 1];
#pragma unroll
    for (int j = 0; j < 4; ++j)
        cb[b * NCHUNK + t * 4 + j] = b * CAP + excl + loc[j];
    if (t == 255) btot[b] = ts[255];
}

// ---- A1: compute msg, scatter records into bucket regions ------------------
// record int4: {dst_local, src, w_bits, msg_bits}
__global__ __launch_bounds__(256) void a1_scatter(
    const int* __restrict__ ei, const float* __restrict__ ea,
    const float* __restrict__ x,
    const float* __restrict__ cg_wf, const float* __restrict__ cg_bf,
    const float* __restrict__ cg_ws, const float* __restrict__ cg_bs,
    const int* __restrict__ cb, int4* __restrict__ rec)
{
    __shared__ int cur[NB];
    const int c = blockIdx.x;
    for (int i = threadIdx.x; i < NB; i += 256) cur[i] = cb[i * NCHUNK + c];
    __syncthreads();
    const float wf0 = cg_wf[0], wf1 = cg_wf[1], wf2 = cg_wf[2], bf = cg_bf[0];
    const float s0 = cg_ws[0], s1 = cg_ws[1], s2 = cg_ws[2], bs = cg_bs[0];
    const size_t base = (size_t)c * (EPC / 4);
    const int4* src4p = (const int4*)ei + base;
    const int4* dst4p = (const int4*)(ei + N_EDGES) + base;
    const float4* w4p = (const float4*)ea + base;
    for (int i = threadIdx.x; i < EPC / 4; i += 256) {
        const int4 s4 = src4p[i];
        const int4 d4 = dst4p[i];
        const float4 w4 = w4p[i];
        const int* sp = (const int*)&s4;
        const int* dp = (const int*)&d4;
        const float* wp = (const float*)&w4;
#pragma unroll
        for (int q = 0; q < 4; ++q) {
            const int src = sp[q], dst = dp[q];
            const float w = wp[q];
            const float xs = x[src], xd = x[dst];
            const float f = fmaf(wf0, xd, fmaf(wf1, xs, fmaf(wf2, w, bf)));
            const float sv = fmaf(s0, xd, fmaf(s1, xs, fmaf(s2, w, bs)));
            const float msg = sigmoid_f(f) * softplus_f(sv);
            const int b = dst >> BSH;
            const int slot = atomicAdd(&cur[b], 1);
            rec[slot] = make_int4(dst & (NODES_PB - 1), src,
                                  __float_as_int(w), __float_as_int(msg));
        }
    }
}

// ---- B1: LDS-accumulate msg & deg per bucket slice -------------------------
__global__ __launch_bounds__(512) void b1_accum(
    const int4* __restrict__ rec, const int* __restrict__ btot,
    float* __restrict__ part1)
{
    __shared__ float lm[NODES_PB];
    __shared__ float ld[NODES_PB];
    const int b = blockIdx.x / PWG, p = blockIdx.x % PWG;
    for (int i = threadIdx.x; i < NODES_PB; i += 512) { lm[i] = 0.0f; ld[i] = 0.0f; }
    __syncthreads();
    const int tot = btot[b];
    const int per = (tot + PWG - 1) / PWG;
    const int s0 = p * per;
    const int s1 = min(tot, s0 + per);
    const int4* r = rec + (size_t)b * CAP;
    int i = s0 + (int)threadIdx.x;
    for (; i + 512 < s1; i += 1024) {
        const int4 v0 = r[i];
        const int4 v1 = r[i + 512];
        atomicAdd(&lm[v0.x], __int_as_float(v0.w));
        atomicAdd(&ld[v0.x], __int_as_float(v0.z));
        atomicAdd(&lm[v1.x], __int_as_float(v1.w));
        atomicAdd(&ld[v1.x], __int_as_float(v1.z));
    }
    for (; i < s1; i += 512) {
        const int4 v0 = r[i];
        atomicAdd(&lm[v0.x], __int_as_float(v0.w));
        atomicAdd(&ld[v0.x], __int_as_float(v0.z));
    }
    __syncthreads();
    float* pm = part1 + (size_t)(b * PWG + p) * NODES_PB;
    float* pd = part1 + (size_t)NB * PWG * NODES_PB + (size_t)(b * PWG + p) * NODES_PB;
    for (int k = threadIdx.x; k < NODES_PB; k += 512) { pm[k] = lm[k]; pd[k] = ld[k]; }
}

// ---- C1: combine partials + node mid (h, dinv, a) --------------------------
__global__ __launch_bounds__(256) void c1_nodemid(
    const float* __restrict__ part1, const float* __restrict__ x,
    const float* __restrict__ gcn_w,
    float* __restrict__ dinv, float* __restrict__ a)
{
    const int n = blockIdx.x * 256 + threadIdx.x;
    const int b = n >> BSH, dl = n & (NODES_PB - 1);
    const float* pm = part1 + (size_t)b * PWG * NODES_PB + dl;
    const float* pd = part1 + (size_t)NB * PWG * NODES_PB + (size_t)b * PWG * NODES_PB + dl;
    float m = 0.0f, d = 0.0f;
#pragma unroll
    for (int p = 0; p < PWG; ++p) {
        m += pm[(size_t)p * NODES_PB];
        d += pd[(size_t)p * NODES_PB];
    }
    const float h = fmaxf(x[n] + m, 0.0f);
    const float di = (d > 0.0f) ? (1.0f / sqrtf(fmaxf(d, 1e-12f))) : 0.0f;
    dinv[n] = di;
    a[n] = di * h * gcn_w[0];
}

// ---- B2: LDS-accumulate s[dst] += a[src]*w ---------------------------------
__global__ __launch_bounds__(512) void b2_accum(
    const int4* __restrict__ rec, const int* __restrict__ btot,
    const float* __restrict__ a, float* __restrict__ part2)
{
    __shared__ float ls[NODES_PB];
    const int b = blockIdx.x / PWG, p = blockIdx.x % PWG;
    for (int i = threadIdx.x; i < NODES_PB; i += 512) ls[i] = 0.0f;
    __syncthreads();
    const int tot = btot[b];
    const int per = (tot + PWG - 1) / PWG;
    const int s0 = p * per;
    const int s1 = min(tot, s0 + per);
    const int4* r = rec + (size_t)b * CAP;
    int i = s0 + (int)threadIdx.x;
    for (; i + 512 < s1; i += 1024) {
        const int4 v0 = r[i];
        const int4 v1 = r[i + 512];
        const float a0 = a[v0.y];
        const float a1 = a[v1.y];
        atomicAdd(&ls[v0.x], a0 * __int_as_float(v0.z));
        atomicAdd(&ls[v1.x], a1 * __int_as_float(v1.z));
    }
    for (; i < s1; i += 512) {
        const int4 v0 = r[i];
        atomicAdd(&ls[v0.x], a[v0.y] * __int_as_float(v0.z));
    }
    __syncthreads();
    float* ps = part2 + (size_t)(b * PWG + p) * NODES_PB;
    for (int k = threadIdx.x; k < NODES_PB; k += 512) ps[k] = ls[k];
}

// ---- C2: combine partials + node fin ---------------------------------------
__global__ __launch_bounds__(256) void c2_nodefin(
    const float* __restrict__ part2, const float* __restrict__ dinv,
    const float* __restrict__ gcn_b, float* __restrict__ hfin)
{
    const int n = blockIdx.x * 256 + threadIdx.x;
    const int b = n >> BSH, dl = n & (NODES_PB - 1);
    const float* ps = part2 + (size_t)b * PWG * NODES_PB + dl;
    float s = 0.0f;
#pragma unroll
    for (int p = 0; p < PWG; ++p) s += ps[(size_t)p * NODES_PB];
    hfin[n] = fmaxf(fmaf(dinv[n], s, gcn_b[0]), 0.0f);
}

// ============================ fallback (atomic) path ========================

__global__ __launch_bounds__(256) void edge_pass1(
    const int* __restrict__ ei, const float* __restrict__ ea,
    const float* __restrict__ x,
    const float* __restrict__ cg_wf, const float* __restrict__ cg_bf,
    const float* __restrict__ cg_ws, const float* __restrict__ cg_bs,
    float* __restrict__ msg_sum, float* __restrict__ deg)
{
    const float wf0 = cg_wf[0], wf1 = cg_wf[1], wf2 = cg_wf[2], bf = cg_bf[0];
    const float s0 = cg_ws[0], s1 = cg_ws[1], s2 = cg_ws[2], bs = cg_bs[0];
    const int t = blockIdx.x * 256 + threadIdx.x;
    const int4 src4 = ((const int4*)ei)[t];
    const int4 dst4 = ((const int4*)(ei + N_EDGES))[t];
    const float4 w4 = ((const float4*)ea)[t];
    const int* sp = (const int*)&src4;
    const int* dp = (const int*)&dst4;
    const float* wp = (const float*)&w4;
#pragma unroll
    for (int q = 0; q < 4; ++q) {
        const int src = sp[q], dst = dp[q];
        const float w = wp[q];
        const float xs = x[src], xd = x[dst];
        const float f = fmaf(wf0, xd, fmaf(wf1, xs, fmaf(wf2, w, bf)));
        const float s = fmaf(s0, xd, fmaf(s1, xs, fmaf(s2, w, bs)));
        const float msg = sigmoid_f(f) * softplus_f(s);
        unsafeAtomicAdd(&msg_sum[dst], msg);
        unsafeAtomicAdd(&deg[dst], w);
    }
}

__global__ __launch_bounds__(256) void node_mid(
    const float* __restrict__ x, const float* __restrict__ msg_sum,
    float* __restrict__ deg_dinv, float* __restrict__ a,
    const float* __restrict__ gcn_w)
{
    const int i = blockIdx.x * 256 + threadIdx.x;
    const float gw = gcn_w[0];
    const float h = fmaxf(x[i] + msg_sum[i], 0.0f);
    const float d = deg_dinv[i];
    const float dinv = (d > 0.0f) ? (1.0f / sqrtf(fmaxf(d, 1e-12f))) : 0.0f;
    deg_dinv[i] = dinv;
    a[i] = dinv * h * gw;
}

__global__ __launch_bounds__(256) void edge_pass2(
    const int* __restrict__ ei, const float* __restrict__ ea,
    const float* __restrict__ a, float* __restrict__ s)
{
    const int t = blockIdx.x * 256 + threadIdx.x;
    const int4 src4 = ((const int4*)ei)[t];
    const int4 dst4 = ((const int4*)(ei + N_EDGES))[t];
    const float4 w4 = ((const float4*)ea)[t];
    const int* sp = (const int*)&src4;
    const int* dp = (const int*)&dst4;
    const float* wp = (const float*)&w4;
#pragma unroll
    for (int q = 0; q < 4; ++q)
        unsafeAtomicAdd(&s[dp[q]], a[sp[q]] * wp[q]);
}

__global__ __launch_bounds__(256) void node_fin(
    const float* __restrict__ dinv, const float* __restrict__ s,
    const float* __restrict__ gcn_b, float* __restrict__ hfin)
{
    const int i = blockIdx.x * 256 + threadIdx.x;
    hfin[i] = fmaxf(fmaf(dinv[i], s[i], gcn_b[0]), 0.0f);
}

// ============================ dense tail ====================================

__global__ __launch_bounds__(256) void fold_bn(
    const float* __restrict__ l3_w, const float* __restrict__ l3_b,
    const float* __restrict__ g, const float* __restrict__ be,
    float* __restrict__ w3f, float* __restrict__ b3f)
{
    const int idx = blockIdx.x * 256 + threadIdx.x;     // 65536
    const int j = idx >> 6, k = idx & 63;
    const float invs = 1.0f / sqrtf(1.0f + 1e-5f);
    const float sc = g[j] * invs;
    w3f[idx] = l3_w[idx] * sc;
    if (k == 0) b3f[j] = fmaf(l3_b[j], sc, be[j]);
}

__global__ __launch_bounds__(256) void gemm1(
    const float* __restrict__ A, const float* __restrict__ W,
    const float* __restrict__ bias, float* __restrict__ C)
{
    __shared__ float As[64][68];
    __shared__ float Ws[64][68];
    const int bj = blockIdx.x, bi = blockIdx.y;
    const int t = threadIdx.x;
#pragma unroll
    for (int q2 = 0; q2 < 4; ++q2) {
        const int idx = t + 256 * q2;
        const int r = idx >> 4, c = idx & 15;
        const float4 va = *(const float4*)(A + (size_t)(bi * 64 + r) * 64 + c * 4);
        const float4 vw = *(const float4*)(W + (size_t)(bj * 64 + r) * 64 + c * 4);
        As[c*4+0][r] = va.x; As[c*4+1][r] = va.y; As[c*4+2][r] = va.z; As[c*4+3][r] = va.w;
        Ws[c*4+0][r] = vw.x; Ws[c*4+1][r] = vw.y; Ws[c*4+2][r] = vw.z; Ws[c*4+3][r] = vw.w;
    }
    __syncthreads();
    const int tx = t & 15, ty = t >> 4;
    const int i0 = ty * 4, j0 = tx * 4;
    float acc[4][4] = {};
#pragma unroll 16
    for (int k = 0; k < 64; ++k) {
        const float4 av = *(const float4*)&As[k][i0];
        const float4 wv = *(const float4*)&Ws[k][j0];
        const float* ap = (const float*)&av;
        const float* wp = (const float*)&wv;
#pragma unroll
        for (int ii = 0; ii < 4; ++ii)
#pragma unroll
            for (int jj = 0; jj < 4; ++jj)
                acc[ii][jj] = fmaf(ap[ii], wp[jj], acc[ii][jj]);
    }
    const int gj = bj * 64 + j0;
    const float4 bv = *(const float4*)(bias + gj);
#pragma unroll
    for (int ii = 0; ii < 4; ++ii) {
        const int gi = bi * 64 + i0 + ii;
        float4 o;
        o.x = fmaxf(acc[ii][0] + bv.x, 0.0f);
        o.y = fmaxf(acc[ii][1] + bv.y, 0.0f);
        o.z = fmaxf(acc[ii][2] + bv.z, 0.0f);
        o.w = fmaxf(acc[ii][3] + bv.w, 0.0f);
        *(float4*)(C + (size_t)gi * H1 + gj) = o;
    }
}

__global__ __launch_bounds__(256) void gemm2(
    const float* __restrict__ H, const float* __restrict__ W,
    const float* __restrict__ bias, float* __restrict__ O)
{
    __shared__ float Hs[64][36];
    __shared__ float Ws[64][132];
    const int bi = blockIdx.x;
    const int t = threadIdx.x;
    const int tx = t & 31, ty = t >> 5;
    const int i0 = ty * 4, j0 = tx * 4;
    float acc[4][4] = {};
    for (int kc = 0; kc < H1; kc += 64) {
#pragma unroll
        for (int q2 = 0; q2 < 2; ++q2) {
            const int idx = t + 256 * q2;
            const int r = idx >> 4, c = idx & 15;
            const float4 v = *(const float4*)(H + (size_t)(bi * 32 + r) * H1 + kc + c * 4);
            Hs[c*4+0][r] = v.x; Hs[c*4+1][r] = v.y; Hs[c*4+2][r] = v.z; Hs[c*4+3][r] = v.w;
        }
#pragma unroll
        for (int q2 = 0; q2 < 8; ++q2) {
            const int idx = t + 256 * q2;
            const int r = idx >> 4, c = idx & 15;
            const float4 v = *(const float4*)(W + (size_t)r * H1 + kc + c * 4);
            Ws[c*4+0][r] = v.x; Ws[c*4+1][r] = v.y; Ws[c*4+2][r] = v.z; Ws[c*4+3][r] = v.w;
        }
        __syncthreads();
#pragma unroll 16
        for (int k = 0; k < 64; ++k) {
            const float4 hv = *(const float4*)&Hs[k][i0];
            const float4 wv = *(const float4*)&Ws[k][j0];
            const float* hp = (const float*)&hv;
            const float* wp = (const float*)&wv;
#pragma unroll
            for (int ii = 0; ii < 4; ++ii)
#pragma unroll
                for (int jj = 0; jj < 4; ++jj)
                    acc[ii][jj] = fmaf(hp[ii], wp[jj], acc[ii][jj]);
        }
        __syncthreads();
    }
    const float4 bv = *(const float4*)(bias + j0);
#pragma unroll
    for (int ii = 0; ii < 4; ++ii) {
        const int gi = bi * 32 + i0 + ii;
        float4 o;
        o.x = fmaxf(acc[ii][0] + bv.x, 0.0f);
        o.y = fmaxf(acc[ii][1] + bv.y, 0.0f);
        o.z = fmaxf(acc[ii][2] + bv.z, 0.0f);
        o.w = fmaxf(acc[ii][3] + bv.w, 0.0f);
        *(float4*)(O + (size_t)gi * DOUT + j0) = o;
    }
}

// ============================ launch ========================================

extern "C" void kernel_launch(void* const* d_in, const int* in_sizes, int n_in,
                              void* d_out, int out_size, void* d_ws, size_t ws_size,
                              hipStream_t stream) {
    const float* x     = (const float*)d_in[0];
    const float* ea    = (const float*)d_in[1];
    const float* cg_wf = (const float*)d_in[2];
    const float* cg_bf = (const float*)d_in[3];
    const float* cg_ws = (const float*)d_in[4];
    const float* cg_bs = (const float*)d_in[5];
    const float* gcn_w = (const float*)d_in[6];
    const float* gcn_b = (const float*)d_in[7];
    const float* l3_w  = (const float*)d_in[8];
    const float* l3_b  = (const float*)d_in[9];
    const float* bn_g  = (const float*)d_in[10];
    const float* bn_b  = (const float*)d_in[11];
    const float* l4_w  = (const float*)d_in[12];
    const float* l4_b  = (const float*)d_in[13];
    const int*   ei    = (const int*)d_in[14];
    float* out = (float*)d_out;
    char* ws = (char*)d_ws;

    // bucketed-path workspace layout
    const size_t off_rec   = 0;
    const size_t off_cc    = off_rec + (size_t)NB * CAP * 16;        // 285,212,672
    const size_t off_cb    = off_cc + (size_t)NCHUNK * NB * 4;
    const size_t off_btot  = off_cb + (size_t)NCHUNK * NB * 4;
    const size_t off_p1    = off_btot + 4096;
    const size_t off_p2    = off_p1 + (size_t)NB * PWG * NODES_PB * 2 * 4;
    const size_t off_dinv  = off_p2 + (size_t)NB * PWG * NODES_PB * 4;
    const size_t off_a     = off_dinv + (size_t)N_NODES * 4;
    const size_t off_hfin  = off_a + (size_t)N_NODES * 4;
    const size_t off_h3    = off_hfin + (size_t)N_NODES * 4;
    const size_t off_w3    = off_h3 + (size_t)8192 * H1 * 4;
    const size_t off_b3    = off_w3 + (size_t)H1 * 64 * 4;
    const size_t required  = off_b3 + (size_t)H1 * 4;

    if (ws_size >= required) {
        int4*  rec   = (int4*)(ws + off_rec);
        int*   cc    = (int*)(ws + off_cc);
        int*   cb    = (int*)(ws + off_cb);
        int*   btot  = (int*)(ws + off_btot);
        float* p1    = (float*)(ws + off_p1);
        float* p2    = (float*)(ws + off_p2);
        float* dinv  = (float*)(ws + off_dinv);
        float* a     = (float*)(ws + off_a);
        float* hfin  = (float*)(ws + off_hfin);
        float* h3    = (float*)(ws + off_h3);
        float* w3    = (float*)(ws + off_w3);
        float* b3    = (float*)(ws + off_b3);

        fold_bn<<<256, 256, 0, stream>>>(l3_w, l3_b, bn_g, bn_b, w3, b3);
        a0_count<<<NCHUNK, 256, 0, stream>>>(ei, cc);
        a_scan<<<NB, 256, 0, stream>>>(cc, cb, btot);
        a1_scatter<<<NCHUNK, 256, 0, stream>>>(ei, ea, x, cg_wf, cg_bf, cg_ws, cg_bs, cb, rec);
        b1_accum<<<NB * PWG, 512, 0, stream>>>(rec, btot, p1);
        c1_nodemid<<<N_NODES / 256, 256, 0, stream>>>(p1, x, gcn_w, dinv, a);
        b2_accum<<<NB * PWG, 512, 0, stream>>>(rec, btot, a, p2);
        c2_nodefin<<<N_NODES / 256, 256, 0, stream>>>(p2, dinv, gcn_b, hfin);
        gemm1<<<dim3(16, 128), 256, 0, stream>>>(hfin, w3, b3, h3);
        gemm2<<<256, 256, 0, stream>>>(h3, l4_w, l4_b, out);
    } else {
        // fallback: device-atomic path (fits in ~42 MB)
        float* buf_msg  = (float*)(ws + 0);
        float* buf_deg  = (float*)(ws + (size_t)2097152);
        float* buf_a    = (float*)(ws + (size_t)4194304);
        float* buf_hfin = (float*)(ws + (size_t)6291456);
        float* buf_h3   = (float*)(ws + (size_t)8388608);
        float* buf_w3   = (float*)(ws + (size_t)41943040);
        float* buf_b3   = (float*)(ws + (size_t)42205184);

        hipMemsetAsync(buf_msg, 0, (size_t)N_NODES * 4, stream);
        hipMemsetAsync(buf_deg, 0, (size_t)N_NODES * 4, stream);
        fold_bn<<<256, 256, 0, stream>>>(l3_w, l3_b, bn_g, bn_b, buf_w3, buf_b3);
        edge_pass1<<<N_EDGES / 4 / 256, 256, 0, stream>>>(
            ei, ea, x, cg_wf, cg_bf, cg_ws, cg_bs, buf_msg, buf_deg);
        node_mid<<<N_NODES / 256, 256, 0, stream>>>(x, buf_msg, buf_deg, buf_a, gcn_w);
        hipMemsetAsync(buf_msg, 0, (size_t)N_NODES * 4, stream);
        edge_pass2<<<N_EDGES / 4 / 256, 256, 0, stream>>>(ei, ea, buf_a, buf_msg);
        node_fin<<<N_NODES / 256, 256, 0, stream>>>(buf_deg, buf_msg, gcn_b, buf_hfin);
        gemm1<<<dim3(16, 128), 256, 0, stream>>>(buf_hfin, buf_w3, buf_b3, buf_h3);
        gemm2<<<256, 256, 0, stream>>>(buf_h3, l4_w, l4_b, out);
    }
}

// Round 3
// 931.710 us; speedup vs baseline: 2.9164x; 1.0203x over previous
//
#include <hip/hip_runtime.h>
#include <math.h>

#define N_NODES 524288
#define N_EDGES 16777216
#define H1      1024
#define DOUT    128

// bucketed-scatter parameters
#define NB        64               // buckets
#define BSH       13               // log2(nodes per bucket)
#define NODES_PB  8192             // nodes per bucket
#define NCHUNK    1024             // edge chunks (one workgroup each)
#define EPC       (N_EDGES / NCHUNK)   // 16384 edges per chunk
#define CAP       278528           // per-bucket record capacity (262144 avg + 16K slack), %16==0
#define PWG       8                // workgroups per bucket in accumulate phases
#define GBUF      64               // LDS staging slots per bucket in a1
#define GSTR      65               // padded stride (kills flush bank conflicts)

__device__ __forceinline__ float sigmoid_f(float v) {
    return 1.0f / (1.0f + __expf(-v));
}
__device__ __forceinline__ float softplus_f(float v) {
    return fmaxf(v, 0.0f) + log1pf(__expf(-fabsf(v)));
}

// ============================ bucketed path =================================

// ---- A1: compute msg, LDS-stage records per bucket, flush contiguously -----
// record (SoA): pk = (src<<13)|dst_local, w, msg
__global__ __launch_bounds__(256) void a1_bin(
    const int* __restrict__ ei, const float* __restrict__ ea,
    const float* __restrict__ x,
    const float* __restrict__ cg_wf, const float* __restrict__ cg_bf,
    const float* __restrict__ cg_ws, const float* __restrict__ cg_bs,
    int* __restrict__ gcur,
    unsigned int* __restrict__ pk_g, float* __restrict__ w_g,
    float* __restrict__ msg_g)
{
    __shared__ unsigned int pk_s[NB * GSTR];
    __shared__ float w_s[NB * GSTR];
    __shared__ float msg_s[NB * GSTR];
    __shared__ int cnt[NB];
    __shared__ int gpos[NB];

    const int c = blockIdx.x, t = threadIdx.x;
    const float wf0 = cg_wf[0], wf1 = cg_wf[1], wf2 = cg_wf[2], bf = cg_bf[0];
    const float s0c = cg_ws[0], s1c = cg_ws[1], s2c = cg_ws[2], bsc = cg_bs[0];

    const size_t base = (size_t)c * (EPC / 4);
    const int4* src4p = (const int4*)ei + base;
    const int4* dst4p = (const int4*)(ei + N_EDGES) + base;
    const float4* w4p = (const float4*)ea + base;

    for (int round = 0; round < EPC / 4 / 256; ++round) {   // 16 rounds
        if (t < NB) cnt[t] = 0;
        __syncthreads();

        const int i = round * 256 + t;
        const int4 s4 = src4p[i];
        const int4 d4 = dst4p[i];
        const float4 w4 = w4p[i];
        const int* sp = (const int*)&s4;
        const int* dp = (const int*)&d4;
        const float* wp = (const float*)&w4;
#pragma unroll
        for (int q = 0; q < 4; ++q) {
            const int src = sp[q], dst = dp[q];
            const float w = wp[q];
            const float xs = x[src], xd = x[dst];
            const float f = fmaf(wf0, xd, fmaf(wf1, xs, fmaf(wf2, w, bf)));
            const float sv = fmaf(s0c, xd, fmaf(s1c, xs, fmaf(s2c, w, bsc)));
            const float msg = sigmoid_f(f) * softplus_f(sv);
            const int b = dst >> BSH;
            const unsigned int pk = ((unsigned int)src << 13) |
                                    (unsigned int)(dst & (NODES_PB - 1));
            const int pos = atomicAdd(&cnt[b], 1);
            if (pos < GBUF) {
                pk_s[b * GSTR + pos] = pk;
                w_s[b * GSTR + pos] = w;
                msg_s[b * GSTR + pos] = msg;
            } else {
                // overflow spill (statistically never for random dst)
                const int o = atomicAdd(&gcur[b], 1);
                const size_t g = (size_t)b * CAP + o;
                pk_g[g] = pk; w_g[g] = w; msg_g[g] = msg;
            }
        }
        __syncthreads();

        if (t < NB) {
            const int cc2 = min(cnt[t], GBUF);
            gpos[t] = atomicAdd(&gcur[t], cc2);
        }
        __syncthreads();

        const int b = t >> 2, j = t & 3;
        const int cc2 = min(cnt[b], GBUF);
        const size_t gb = (size_t)b * CAP + gpos[b];
        for (int k = j; k < cc2; k += 4) {
            pk_g[gb + k]  = pk_s[b * GSTR + k];
            w_g[gb + k]   = w_s[b * GSTR + k];
            msg_g[gb + k] = msg_s[b * GSTR + k];
        }
        __syncthreads();
    }
}

// ---- B1: LDS-accumulate msg & deg per bucket slice -------------------------
__global__ __launch_bounds__(512) void b1_accum(
    const unsigned int* __restrict__ pk_g, const float* __restrict__ w_g,
    const float* __restrict__ msg_g, const int* __restrict__ btot,
    float* __restrict__ part1)
{
    __shared__ float lm[NODES_PB];
    __shared__ float ld[NODES_PB];
    const int b = blockIdx.x / PWG, p = blockIdx.x % PWG;
    for (int i = threadIdx.x; i < NODES_PB; i += 512) { lm[i] = 0.0f; ld[i] = 0.0f; }
    __syncthreads();
    const int tot = btot[b];
    const int per = (((tot + PWG - 1) / PWG) + 3) & ~3;
    const int s0 = p * per;
    const int s1 = min(tot, s0 + per);
    const size_t gb = (size_t)b * CAP;
    if (s1 > s0) {
        const int nvec = (s1 - s0) >> 2;
        const uint4* pk4 = (const uint4*)(pk_g + gb + s0);
        const float4* w4 = (const float4*)(w_g + gb + s0);
        const float4* m4 = (const float4*)(msg_g + gb + s0);
        for (int k = threadIdx.x; k < nvec; k += 512) {
            const uint4 pv = pk4[k];
            const float4 wv = w4[k];
            const float4 mv = m4[k];
            atomicAdd(&lm[pv.x & (NODES_PB - 1)], mv.x);
            atomicAdd(&ld[pv.x & (NODES_PB - 1)], wv.x);
            atomicAdd(&lm[pv.y & (NODES_PB - 1)], mv.y);
            atomicAdd(&ld[pv.y & (NODES_PB - 1)], wv.y);
            atomicAdd(&lm[pv.z & (NODES_PB - 1)], mv.z);
            atomicAdd(&ld[pv.z & (NODES_PB - 1)], wv.z);
            atomicAdd(&lm[pv.w & (NODES_PB - 1)], mv.w);
            atomicAdd(&ld[pv.w & (NODES_PB - 1)], wv.w);
        }
        for (int k = s0 + (nvec << 2) + (int)threadIdx.x; k < s1; k += 512) {
            const unsigned int pv = pk_g[gb + k];
            atomicAdd(&lm[pv & (NODES_PB - 1)], msg_g[gb + k]);
            atomicAdd(&ld[pv & (NODES_PB - 1)], w_g[gb + k]);
        }
    }
    __syncthreads();
    float* pm = part1 + (size_t)(b * PWG + p) * NODES_PB;
    float* pd = part1 + (size_t)NB * PWG * NODES_PB + (size_t)(b * PWG + p) * NODES_PB;
    for (int k = threadIdx.x; k < NODES_PB; k += 512) { pm[k] = lm[k]; pd[k] = ld[k]; }
}

// ---- C1: combine partials + node mid (h, dinv, a) --------------------------
__global__ __launch_bounds__(256) void c1_nodemid(
    const float* __restrict__ part1, const float* __restrict__ x,
    const float* __restrict__ gcn_w,
    float* __restrict__ dinv, float* __restrict__ a)
{
    const int n = blockIdx.x * 256 + threadIdx.x;
    const int b = n >> BSH, dl = n & (NODES_PB - 1);
    const float* pm = part1 + (size_t)b * PWG * NODES_PB + dl;
    const float* pd = part1 + (size_t)NB * PWG * NODES_PB + (size_t)b * PWG * NODES_PB + dl;
    float m = 0.0f, d = 0.0f;
#pragma unroll
    for (int p = 0; p < PWG; ++p) {
        m += pm[(size_t)p * NODES_PB];
        d += pd[(size_t)p * NODES_PB];
    }
    const float h = fmaxf(x[n] + m, 0.0f);
    const float di = (d > 0.0f) ? (1.0f / sqrtf(fmaxf(d, 1e-12f))) : 0.0f;
    dinv[n] = di;
    a[n] = di * h * gcn_w[0];
}

// ---- B2: LDS-accumulate s[dst] += a[src]*w ---------------------------------
__global__ __launch_bounds__(512) void b2_accum(
    const unsigned int* __restrict__ pk_g, const float* __restrict__ w_g,
    const int* __restrict__ btot, const float* __restrict__ a,
    float* __restrict__ part2)
{
    __shared__ float ls[NODES_PB];
    const int b = blockIdx.x / PWG, p = blockIdx.x % PWG;
    for (int i = threadIdx.x; i < NODES_PB; i += 512) ls[i] = 0.0f;
    __syncthreads();
    const int tot = btot[b];
    const int per = (((tot + PWG - 1) / PWG) + 3) & ~3;
    const int s0 = p * per;
    const int s1 = min(tot, s0 + per);
    const size_t gb = (size_t)b * CAP;
    if (s1 > s0) {
        const int nvec = (s1 - s0) >> 2;
        const uint4* pk4 = (const uint4*)(pk_g + gb + s0);
        const float4* w4 = (const float4*)(w_g + gb + s0);
        for (int k = threadIdx.x; k < nvec; k += 512) {
            const uint4 pv = pk4[k];
            const float4 wv = w4[k];
            atomicAdd(&ls[pv.x & (NODES_PB - 1)], a[pv.x >> 13] * wv.x);
            atomicAdd(&ls[pv.y & (NODES_PB - 1)], a[pv.y >> 13] * wv.y);
            atomicAdd(&ls[pv.z & (NODES_PB - 1)], a[pv.z >> 13] * wv.z);
            atomicAdd(&ls[pv.w & (NODES_PB - 1)], a[pv.w >> 13] * wv.w);
        }
        for (int k = s0 + (nvec << 2) + (int)threadIdx.x; k < s1; k += 512) {
            const unsigned int pv = pk_g[gb + k];
            atomicAdd(&ls[pv & (NODES_PB - 1)], a[pv >> 13] * w_g[gb + k]);
        }
    }
    __syncthreads();
    float* ps = part2 + (size_t)(b * PWG + p) * NODES_PB;
    for (int k = threadIdx.x; k < NODES_PB; k += 512) ps[k] = ls[k];
}

// ---- C2: combine partials + node fin ---------------------------------------
__global__ __launch_bounds__(256) void c2_nodefin(
    const float* __restrict__ part2, const float* __restrict__ dinv,
    const float* __restrict__ gcn_b, float* __restrict__ hfin)
{
    const int n = blockIdx.x * 256 + threadIdx.x;
    const int b = n >> BSH, dl = n & (NODES_PB - 1);
    const float* ps = part2 + (size_t)b * PWG * NODES_PB + dl;
    float s = 0.0f;
#pragma unroll
    for (int p = 0; p < PWG; ++p) s += ps[(size_t)p * NODES_PB];
    hfin[n] = fmaxf(fmaf(dinv[n], s, gcn_b[0]), 0.0f);
}

// ============================ fallback (atomic) path ========================

__global__ __launch_bounds__(256) void edge_pass1(
    const int* __restrict__ ei, const float* __restrict__ ea,
    const float* __restrict__ x,
    const float* __restrict__ cg_wf, const float* __restrict__ cg_bf,
    const float* __restrict__ cg_ws, const float* __restrict__ cg_bs,
    float* __restrict__ msg_sum, float* __restrict__ deg)
{
    const float wf0 = cg_wf[0], wf1 = cg_wf[1], wf2 = cg_wf[2], bf = cg_bf[0];
    const float s0 = cg_ws[0], s1 = cg_ws[1], s2 = cg_ws[2], bs = cg_bs[0];
    const int t = blockIdx.x * 256 + threadIdx.x;
    const int4 src4 = ((const int4*)ei)[t];
    const int4 dst4 = ((const int4*)(ei + N_EDGES))[t];
    const float4 w4 = ((const float4*)ea)[t];
    const int* sp = (const int*)&src4;
    const int* dp = (const int*)&dst4;
    const float* wp = (const float*)&w4;
#pragma unroll
    for (int q = 0; q < 4; ++q) {
        const int src = sp[q], dst = dp[q];
        const float w = wp[q];
        const float xs = x[src], xd = x[dst];
        const float f = fmaf(wf0, xd, fmaf(wf1, xs, fmaf(wf2, w, bf)));
        const float s = fmaf(s0, xd, fmaf(s1, xs, fmaf(s2, w, bs)));
        const float msg = sigmoid_f(f) * softplus_f(s);
        unsafeAtomicAdd(&msg_sum[dst], msg);
        unsafeAtomicAdd(&deg[dst], w);
    }
}

__global__ __launch_bounds__(256) void node_mid(
    const float* __restrict__ x, const float* __restrict__ msg_sum,
    float* __restrict__ deg_dinv, float* __restrict__ a,
    const float* __restrict__ gcn_w)
{
    const int i = blockIdx.x * 256 + threadIdx.x;
    const float gw = gcn_w[0];
    const float h = fmaxf(x[i] + msg_sum[i], 0.0f);
    const float d = deg_dinv[i];
    const float dinv = (d > 0.0f) ? (1.0f / sqrtf(fmaxf(d, 1e-12f))) : 0.0f;
    deg_dinv[i] = dinv;
    a[i] = dinv * h * gw;
}

__global__ __launch_bounds__(256) void edge_pass2(
    const int* __restrict__ ei, const float* __restrict__ ea,
    const float* __restrict__ a, float* __restrict__ s)
{
    const int t = blockIdx.x * 256 + threadIdx.x;
    const int4 src4 = ((const int4*)ei)[t];
    const int4 dst4 = ((const int4*)(ei + N_EDGES))[t];
    const float4 w4 = ((const float4*)ea)[t];
    const int* sp = (const int*)&src4;
    const int* dp = (const int*)&dst4;
    const float* wp = (const float*)&w4;
#pragma unroll
    for (int q = 0; q < 4; ++q)
        unsafeAtomicAdd(&s[dp[q]], a[sp[q]] * wp[q]);
}

__global__ __launch_bounds__(256) void node_fin(
    const float* __restrict__ dinv, const float* __restrict__ s,
    const float* __restrict__ gcn_b, float* __restrict__ hfin)
{
    const int i = blockIdx.x * 256 + threadIdx.x;
    hfin[i] = fmaxf(fmaf(dinv[i], s[i], gcn_b[0]), 0.0f);
}

// ============================ dense tail ====================================

__global__ __launch_bounds__(256) void fold_bn(
    const float* __restrict__ l3_w, const float* __restrict__ l3_b,
    const float* __restrict__ g, const float* __restrict__ be,
    float* __restrict__ w3f, float* __restrict__ b3f)
{
    const int idx = blockIdx.x * 256 + threadIdx.x;     // 65536
    const int j = idx >> 6, k = idx & 63;
    const float invs = 1.0f / sqrtf(1.0f + 1e-5f);
    const float sc = g[j] * invs;
    w3f[idx] = l3_w[idx] * sc;
    if (k == 0) b3f[j] = fmaf(l3_b[j], sc, be[j]);
}

__global__ __launch_bounds__(256) void gemm1(
    const float* __restrict__ A, const float* __restrict__ W,
    const float* __restrict__ bias, float* __restrict__ C)
{
    __shared__ float As[64][68];
    __shared__ float Ws[64][68];
    const int bj = blockIdx.x, bi = blockIdx.y;
    const int t = threadIdx.x;
#pragma unroll
    for (int q2 = 0; q2 < 4; ++q2) {
        const int idx = t + 256 * q2;
        const int r = idx >> 4, c = idx & 15;
        const float4 va = *(const float4*)(A + (size_t)(bi * 64 + r) * 64 + c * 4);
        const float4 vw = *(const float4*)(W + (size_t)(bj * 64 + r) * 64 + c * 4);
        As[c*4+0][r] = va.x; As[c*4+1][r] = va.y; As[c*4+2][r] = va.z; As[c*4+3][r] = va.w;
        Ws[c*4+0][r] = vw.x; Ws[c*4+1][r] = vw.y; Ws[c*4+2][r] = vw.z; Ws[c*4+3][r] = vw.w;
    }
    __syncthreads();
    const int tx = t & 15, ty = t >> 4;
    const int i0 = ty * 4, j0 = tx * 4;
    float acc[4][4] = {};
#pragma unroll 16
    for (int k = 0; k < 64; ++k) {
        const float4 av = *(const float4*)&As[k][i0];
        const float4 wv = *(const float4*)&Ws[k][j0];
        const float* ap = (const float*)&av;
        const float* wp = (const float*)&wv;
#pragma unroll
        for (int ii = 0; ii < 4; ++ii)
#pragma unroll
            for (int jj = 0; jj < 4; ++jj)
                acc[ii][jj] = fmaf(ap[ii], wp[jj], acc[ii][jj]);
    }
    const int gj = bj * 64 + j0;
    const float4 bv = *(const float4*)(bias + gj);
#pragma unroll
    for (int ii = 0; ii < 4; ++ii) {
        const int gi = bi * 64 + i0 + ii;
        float4 o;
        o.x = fmaxf(acc[ii][0] + bv.x, 0.0f);
        o.y = fmaxf(acc[ii][1] + bv.y, 0.0f);
        o.z = fmaxf(acc[ii][2] + bv.z, 0.0f);
        o.w = fmaxf(acc[ii][3] + bv.w, 0.0f);
        *(float4*)(C + (size_t)gi * H1 + gj) = o;
    }
}

__global__ __launch_bounds__(256) void gemm2(
    const float* __restrict__ H, const float* __restrict__ W,
    const float* __restrict__ bias, float* __restrict__ O)
{
    __shared__ float Hs[64][36];
    __shared__ float Ws[64][132];
    const int bi = blockIdx.x;
    const int t = threadIdx.x;
    const int tx = t & 31, ty = t >> 5;
    const int i0 = ty * 4, j0 = tx * 4;
    float acc[4][4] = {};
    for (int kc = 0; kc < H1; kc += 64) {
#pragma unroll
        for (int q2 = 0; q2 < 2; ++q2) {
            const int idx = t + 256 * q2;
            const int r = idx >> 4, c = idx & 15;
            const float4 v = *(const float4*)(H + (size_t)(bi * 32 + r) * H1 + kc + c * 4);
            Hs[c*4+0][r] = v.x; Hs[c*4+1][r] = v.y; Hs[c*4+2][r] = v.z; Hs[c*4+3][r] = v.w;
        }
#pragma unroll
        for (int q2 = 0; q2 < 8; ++q2) {
            const int idx = t + 256 * q2;
            const int r = idx >> 4, c = idx & 15;
            const float4 v = *(const float4*)(W + (size_t)r * H1 + kc + c * 4);
            Ws[c*4+0][r] = v.x; Ws[c*4+1][r] = v.y; Ws[c*4+2][r] = v.z; Ws[c*4+3][r] = v.w;
        }
        __syncthreads();
#pragma unroll 16
        for (int k = 0; k < 64; ++k) {
            const float4 hv = *(const float4*)&Hs[k][i0];
            const float4 wv = *(const float4*)&Ws[k][j0];
            const float* hp = (const float*)&hv;
            const float* wp = (const float*)&wv;
#pragma unroll
            for (int ii = 0; ii < 4; ++ii)
#pragma unroll
                for (int jj = 0; jj < 4; ++jj)
                    acc[ii][jj] = fmaf(hp[ii], wp[jj], acc[ii][jj]);
        }
        __syncthreads();
    }
    const float4 bv = *(const float4*)(bias + j0);
#pragma unroll
    for (int ii = 0; ii < 4; ++ii) {
        const int gi = bi * 32 + i0 + ii;
        float4 o;
        o.x = fmaxf(acc[ii][0] + bv.x, 0.0f);
        o.y = fmaxf(acc[ii][1] + bv.y, 0.0f);
        o.z = fmaxf(acc[ii][2] + bv.z, 0.0f);
        o.w = fmaxf(acc[ii][3] + bv.w, 0.0f);
        *(float4*)(O + (size_t)gi * DOUT + j0) = o;
    }
}

// ============================ launch ========================================

extern "C" void kernel_launch(void* const* d_in, const int* in_sizes, int n_in,
                              void* d_out, int out_size, void* d_ws, size_t ws_size,
                              hipStream_t stream) {
    const float* x     = (const float*)d_in[0];
    const float* ea    = (const float*)d_in[1];
    const float* cg_wf = (const float*)d_in[2];
    const float* cg_bf = (const float*)d_in[3];
    const float* cg_ws = (const float*)d_in[4];
    const float* cg_bs = (const float*)d_in[5];
    const float* gcn_w = (const float*)d_in[6];
    const float* gcn_b = (const float*)d_in[7];
    const float* l3_w  = (const float*)d_in[8];
    const float* l3_b  = (const float*)d_in[9];
    const float* bn_g  = (const float*)d_in[10];
    const float* bn_b  = (const float*)d_in[11];
    const float* l4_w  = (const float*)d_in[12];
    const float* l4_b  = (const float*)d_in[13];
    const int*   ei    = (const int*)d_in[14];
    float* out = (float*)d_out;
    char* ws = (char*)d_ws;

    // bucketed-path workspace layout (12B SoA records)
    const size_t off_pk    = 0;
    const size_t off_w     = off_pk + (size_t)NB * CAP * 4;      // 71,303,168 each
    const size_t off_msg   = off_w + (size_t)NB * CAP * 4;
    const size_t off_gcur  = off_msg + (size_t)NB * CAP * 4;
    const size_t off_p1    = off_gcur + 1024;
    const size_t off_p2    = off_p1 + (size_t)NB * PWG * NODES_PB * 2 * 4;
    const size_t off_dinv  = off_p2 + (size_t)NB * PWG * NODES_PB * 4;
    const size_t off_a     = off_dinv + (size_t)N_NODES * 4;
    const size_t off_hfin  = off_a + (size_t)N_NODES * 4;
    const size_t off_h3    = off_hfin + (size_t)N_NODES * 4;
    const size_t off_w3    = off_h3 + (size_t)8192 * H1 * 4;
    const size_t off_b3    = off_w3 + (size_t)H1 * 64 * 4;
    const size_t required  = off_b3 + (size_t)H1 * 4;

    if (ws_size >= required) {
        unsigned int* pk = (unsigned int*)(ws + off_pk);
        float* wg    = (float*)(ws + off_w);
        float* msgg  = (float*)(ws + off_msg);
        int*   gcur  = (int*)(ws + off_gcur);
        float* p1    = (float*)(ws + off_p1);
        float* p2    = (float*)(ws + off_p2);
        float* dinv  = (float*)(ws + off_dinv);
        float* a     = (float*)(ws + off_a);
        float* hfin  = (float*)(ws + off_hfin);
        float* h3    = (float*)(ws + off_h3);
        float* w3    = (float*)(ws + off_w3);
        float* b3    = (float*)(ws + off_b3);

        hipMemsetAsync(gcur, 0, NB * 4, stream);
        fold_bn<<<256, 256, 0, stream>>>(l3_w, l3_b, bn_g, bn_b, w3, b3);
        a1_bin<<<NCHUNK, 256, 0, stream>>>(ei, ea, x, cg_wf, cg_bf, cg_ws, cg_bs,
                                           gcur, pk, wg, msgg);
        b1_accum<<<NB * PWG, 512, 0, stream>>>(pk, wg, msgg, gcur, p1);
        c1_nodemid<<<N_NODES / 256, 256, 0, stream>>>(p1, x, gcn_w, dinv, a);
        b2_accum<<<NB * PWG, 512, 0, stream>>>(pk, wg, gcur, a, p2);
        c2_nodefin<<<N_NODES / 256, 256, 0, stream>>>(p2, dinv, gcn_b, hfin);
        gemm1<<<dim3(16, 128), 256, 0, stream>>>(hfin, w3, b3, h3);
        gemm2<<<256, 256, 0, stream>>>(h3, l4_w, l4_b, out);
    } else {
        // fallback: device-atomic path (fits in ~42 MB)
        float* buf_msg  = (float*)(ws + 0);
        float* buf_deg  = (float*)(ws + (size_t)2097152);
        float* buf_a    = (float*)(ws + (size_t)4194304);
        float* buf_hfin = (float*)(ws + (size_t)6291456);
        float* buf_h3   = (float*)(ws + (size_t)8388608);
        float* buf_w3   = (float*)(ws + (size_t)41943040);
        float* buf_b3   = (float*)(ws + (size_t)42205184);

        hipMemsetAsync(buf_msg, 0, (size_t)N_NODES * 4, stream);
        hipMemsetAsync(buf_deg, 0, (size_t)N_NODES * 4, stream);
        fold_bn<<<256, 256, 0, stream>>>(l3_w, l3_b, bn_g, bn_b, buf_w3, buf_b3);
        edge_pass1<<<N_EDGES / 4 / 256, 256, 0, stream>>>(
            ei, ea, x, cg_wf, cg_bf, cg_ws, cg_bs, buf_msg, buf_deg);
        node_mid<<<N_NODES / 256, 256, 0, stream>>>(x, buf_msg, buf_deg, buf_a, gcn_w);
        hipMemsetAsync(buf_msg, 0, (size_t)N_NODES * 4, stream);
        edge_pass2<<<N_EDGES / 4 / 256, 256, 0, stream>>>(ei, ea, buf_a, buf_msg);
        node_fin<<<N_NODES / 256, 256, 0, stream>>>(buf_deg, buf_msg, gcn_b, buf_hfin);
        gemm1<<<dim3(16, 128), 256, 0, stream>>>(buf_hfin, buf_w3, buf_b3, buf_h3);
        gemm2<<<256, 256, 0, stream>>>(buf_h3, l4_w, l4_b, out);
    }
}

// Round 4
// 879.665 us; speedup vs baseline: 3.0890x; 1.0592x over previous
//
#include <hip/hip_runtime.h>
#include <math.h>

#define N_NODES 524288
#define N_EDGES 16777216
#define H1      1024
#define DOUT    128

// bucketed-scatter parameters
#define NB        64               // buckets
#define BSH       13               // log2(nodes per bucket)
#define NODES_PB  8192             // nodes per bucket
#define EPB       2048             // edges per a1 block
#define NBLK      (N_EDGES / EPB)  // 8192 a1 blocks
#define CAP       278528           // per-bucket record capacity (262144 avg + 16K slack)
#define PWG       8                // workgroups per bucket in accumulate phases

__device__ __forceinline__ float sigmoid_f(float v) {
    return 1.0f / (1.0f + __expf(-v));
}
__device__ __forceinline__ float softplus_f(float v) {
    return fmaxf(v, 0.0f) + log1pf(__expf(-fabsf(v)));
}

// ============================ bucketed path =================================

// ---- A1: compute msg, rank via LDS histogram, direct scatter ---------------
// records (SoA-2): pkw = uint2{(src<<13)|dst_local, w_bits};  msg = float
__global__ __launch_bounds__(256) void a1_bin2(
    const int* __restrict__ ei, const float* __restrict__ ea,
    const float* __restrict__ x,
    const float* __restrict__ cg_wf, const float* __restrict__ cg_bf,
    const float* __restrict__ cg_ws, const float* __restrict__ cg_bs,
    int* __restrict__ gcur,          // [NB*16] padded cursors
    uint2* __restrict__ pkw_g, float* __restrict__ msg_g)
{
    __shared__ int cnt[NB];
    __shared__ int gpos[NB];
    const int c = blockIdx.x, t = threadIdx.x;

    // load 8 edges: records c*2048 + {4t..4t+3} and + {1024+4t..1024+4t+3}
    const int vi0 = c * 512 + t;
    const int vi1 = vi0 + 256;
    const int4 s4a = ((const int4*)ei)[vi0];
    const int4 s4b = ((const int4*)ei)[vi1];
    const int4 d4a = ((const int4*)(ei + N_EDGES))[vi0];
    const int4 d4b = ((const int4*)(ei + N_EDGES))[vi1];
    const float4 w4a = ((const float4*)ea)[vi0];
    const float4 w4b = ((const float4*)ea)[vi1];
    int srcs[8], dsts[8];
    float ws[8];
    srcs[0]=s4a.x; srcs[1]=s4a.y; srcs[2]=s4a.z; srcs[3]=s4a.w;
    srcs[4]=s4b.x; srcs[5]=s4b.y; srcs[6]=s4b.z; srcs[7]=s4b.w;
    dsts[0]=d4a.x; dsts[1]=d4a.y; dsts[2]=d4a.z; dsts[3]=d4a.w;
    dsts[4]=d4b.x; dsts[5]=d4b.y; dsts[6]=d4b.z; dsts[7]=d4b.w;
    ws[0]=w4a.x; ws[1]=w4a.y; ws[2]=w4a.z; ws[3]=w4a.w;
    ws[4]=w4b.x; ws[5]=w4b.y; ws[6]=w4b.z; ws[7]=w4b.w;

    // start x gathers early (overlap with histogram)
    float xs[8], xd[8];
#pragma unroll
    for (int q = 0; q < 8; ++q) { xs[q] = x[srcs[q]]; xd[q] = x[dsts[q]]; }

    if (t < NB) cnt[t] = 0;
    __syncthreads();

    int rank[8];
#pragma unroll
    for (int q = 0; q < 8; ++q)
        rank[q] = atomicAdd(&cnt[dsts[q] >> BSH], 1);
    __syncthreads();

    if (t < NB) gpos[t] = atomicAdd(&gcur[t * 16], cnt[t]);
    __syncthreads();

    const float wf0 = cg_wf[0], wf1 = cg_wf[1], wf2 = cg_wf[2], bf = cg_bf[0];
    const float s0c = cg_ws[0], s1c = cg_ws[1], s2c = cg_ws[2], bsc = cg_bs[0];
#pragma unroll
    for (int q = 0; q < 8; ++q) {
        const int src = srcs[q], dst = dsts[q];
        const float w = ws[q];
        const float f = fmaf(wf0, xd[q], fmaf(wf1, xs[q], fmaf(wf2, w, bf)));
        const float sv = fmaf(s0c, xd[q], fmaf(s1c, xs[q], fmaf(s2c, w, bsc)));
        const float msg = sigmoid_f(f) * softplus_f(sv);
        const int b = dst >> BSH;
        const size_t slot = (size_t)b * CAP + gpos[b] + rank[q];
        const unsigned int pk = ((unsigned int)src << 13) |
                                (unsigned int)(dst & (NODES_PB - 1));
        pkw_g[slot] = make_uint2(pk, __float_as_uint(w));
        msg_g[slot] = msg;
    }
}

// ---- B1: LDS-accumulate msg & deg per bucket slice -------------------------
__global__ __launch_bounds__(1024) void b1_accum(
    const uint2* __restrict__ pkw_g, const float* __restrict__ msg_g,
    const int* __restrict__ gcur, float* __restrict__ part1)
{
    __shared__ float lm[NODES_PB];
    __shared__ float ld[NODES_PB];
    const int b = blockIdx.x / PWG, p = blockIdx.x % PWG;
    for (int i = threadIdx.x; i < NODES_PB; i += 1024) { lm[i] = 0.0f; ld[i] = 0.0f; }
    __syncthreads();
    const int tot = gcur[b * 16];
    const int per = (tot + PWG - 1) / PWG;
    const int s0 = p * per;
    const int s1 = min(tot, s0 + per);
    const size_t gb = (size_t)b * CAP;
    for (int k = s0 + (int)threadIdx.x; k < s1; k += 1024) {
        const uint2 v = pkw_g[gb + k];
        const float m = msg_g[gb + k];
        const int dl = v.x & (NODES_PB - 1);
        atomicAdd(&lm[dl], m);
        atomicAdd(&ld[dl], __uint_as_float(v.y));
    }
    __syncthreads();
    float* pm = part1 + (size_t)(b * PWG + p) * NODES_PB;
    float* pd = part1 + (size_t)NB * PWG * NODES_PB + (size_t)(b * PWG + p) * NODES_PB;
    for (int k = threadIdx.x; k < NODES_PB; k += 1024) { pm[k] = lm[k]; pd[k] = ld[k]; }
}

// ---- C1: combine partials + node mid (h, dinv, a) --------------------------
__global__ __launch_bounds__(256) void c1_nodemid(
    const float* __restrict__ part1, const float* __restrict__ x,
    const float* __restrict__ gcn_w,
    float* __restrict__ dinv, float* __restrict__ a)
{
    const int n = blockIdx.x * 256 + threadIdx.x;
    const int b = n >> BSH, dl = n & (NODES_PB - 1);
    const float* pm = part1 + (size_t)b * PWG * NODES_PB + dl;
    const float* pd = part1 + (size_t)NB * PWG * NODES_PB + (size_t)b * PWG * NODES_PB + dl;
    float m = 0.0f, d = 0.0f;
#pragma unroll
    for (int p = 0; p < PWG; ++p) {
        m += pm[(size_t)p * NODES_PB];
        d += pd[(size_t)p * NODES_PB];
    }
    const float h = fmaxf(x[n] + m, 0.0f);
    const float di = (d > 0.0f) ? (1.0f / sqrtf(fmaxf(d, 1e-12f))) : 0.0f;
    dinv[n] = di;
    a[n] = di * h * gcn_w[0];
}

// ---- B2: LDS-accumulate s[dst] += a[src]*w ---------------------------------
__global__ __launch_bounds__(1024) void b2_accum(
    const uint2* __restrict__ pkw_g, const int* __restrict__ gcur,
    const float* __restrict__ a, float* __restrict__ part2)
{
    __shared__ float ls[NODES_PB];
    const int b = blockIdx.x / PWG, p = blockIdx.x % PWG;
    for (int i = threadIdx.x; i < NODES_PB; i += 1024) ls[i] = 0.0f;
    __syncthreads();
    const int tot = gcur[b * 16];
    const int per = (tot + PWG - 1) / PWG;
    const int s0 = p * per;
    const int s1 = min(tot, s0 + per);
    const size_t gb = (size_t)b * CAP;
    for (int k = s0 + (int)threadIdx.x; k < s1; k += 1024) {
        const uint2 v = pkw_g[gb + k];
        atomicAdd(&ls[v.x & (NODES_PB - 1)], a[v.x >> 13] * __uint_as_float(v.y));
    }
    __syncthreads();
    float* ps = part2 + (size_t)(b * PWG + p) * NODES_PB;
    for (int k = threadIdx.x; k < NODES_PB; k += 1024) ps[k] = ls[k];
}

// ---- C2: combine partials + node fin ---------------------------------------
__global__ __launch_bounds__(256) void c2_nodefin(
    const float* __restrict__ part2, const float* __restrict__ dinv,
    const float* __restrict__ gcn_b, float* __restrict__ hfin)
{
    const int n = blockIdx.x * 256 + threadIdx.x;
    const int b = n >> BSH, dl = n & (NODES_PB - 1);
    const float* ps = part2 + (size_t)b * PWG * NODES_PB + dl;
    float s = 0.0f;
#pragma unroll
    for (int p = 0; p < PWG; ++p) s += ps[(size_t)p * NODES_PB];
    hfin[n] = fmaxf(fmaf(dinv[n], s, gcn_b[0]), 0.0f);
}

// ============================ fallback (atomic) path ========================

__global__ __launch_bounds__(256) void edge_pass1(
    const int* __restrict__ ei, const float* __restrict__ ea,
    const float* __restrict__ x,
    const float* __restrict__ cg_wf, const float* __restrict__ cg_bf,
    const float* __restrict__ cg_ws, const float* __restrict__ cg_bs,
    float* __restrict__ msg_sum, float* __restrict__ deg)
{
    const float wf0 = cg_wf[0], wf1 = cg_wf[1], wf2 = cg_wf[2], bf = cg_bf[0];
    const float s0 = cg_ws[0], s1 = cg_ws[1], s2 = cg_ws[2], bs = cg_bs[0];
    const int t = blockIdx.x * 256 + threadIdx.x;
    const int4 src4 = ((const int4*)ei)[t];
    const int4 dst4 = ((const int4*)(ei + N_EDGES))[t];
    const float4 w4 = ((const float4*)ea)[t];
    const int* sp = (const int*)&src4;
    const int* dp = (const int*)&dst4;
    const float* wp = (const float*)&w4;
#pragma unroll
    for (int q = 0; q < 4; ++q) {
        const int src = sp[q], dst = dp[q];
        const float w = wp[q];
        const float xs = x[src], xd = x[dst];
        const float f = fmaf(wf0, xd, fmaf(wf1, xs, fmaf(wf2, w, bf)));
        const float s = fmaf(s0, xd, fmaf(s1, xs, fmaf(s2, w, bs)));
        const float msg = sigmoid_f(f) * softplus_f(s);
        unsafeAtomicAdd(&msg_sum[dst], msg);
        unsafeAtomicAdd(&deg[dst], w);
    }
}

__global__ __launch_bounds__(256) void node_mid(
    const float* __restrict__ x, const float* __restrict__ msg_sum,
    float* __restrict__ deg_dinv, float* __restrict__ a,
    const float* __restrict__ gcn_w)
{
    const int i = blockIdx.x * 256 + threadIdx.x;
    const float gw = gcn_w[0];
    const float h = fmaxf(x[i] + msg_sum[i], 0.0f);
    const float d = deg_dinv[i];
    const float dinv = (d > 0.0f) ? (1.0f / sqrtf(fmaxf(d, 1e-12f))) : 0.0f;
    deg_dinv[i] = dinv;
    a[i] = dinv * h * gw;
}

__global__ __launch_bounds__(256) void edge_pass2(
    const int* __restrict__ ei, const float* __restrict__ ea,
    const float* __restrict__ a, float* __restrict__ s)
{
    const int t = blockIdx.x * 256 + threadIdx.x;
    const int4 src4 = ((const int4*)ei)[t];
    const int4 dst4 = ((const int4*)(ei + N_EDGES))[t];
    const float4 w4 = ((const float4*)ea)[t];
    const int* sp = (const int*)&src4;
    const int* dp = (const int*)&dst4;
    const float* wp = (const float*)&w4;
#pragma unroll
    for (int q = 0; q < 4; ++q)
        unsafeAtomicAdd(&s[dp[q]], a[sp[q]] * wp[q]);
}

__global__ __launch_bounds__(256) void node_fin(
    const float* __restrict__ dinv, const float* __restrict__ s,
    const float* __restrict__ gcn_b, float* __restrict__ hfin)
{
    const int i = blockIdx.x * 256 + threadIdx.x;
    hfin[i] = fmaxf(fmaf(dinv[i], s[i], gcn_b[0]), 0.0f);
}

// ============================ dense tail ====================================

__global__ __launch_bounds__(256) void fold_bn(
    const float* __restrict__ l3_w, const float* __restrict__ l3_b,
    const float* __restrict__ g, const float* __restrict__ be,
    float* __restrict__ w3f, float* __restrict__ b3f)
{
    const int idx = blockIdx.x * 256 + threadIdx.x;     // 65536
    const int j = idx >> 6, k = idx & 63;
    const float invs = 1.0f / sqrtf(1.0f + 1e-5f);
    const float sc = g[j] * invs;
    w3f[idx] = l3_w[idx] * sc;
    if (k == 0) b3f[j] = fmaf(l3_b[j], sc, be[j]);
}

__global__ __launch_bounds__(256) void gemm1(
    const float* __restrict__ A, const float* __restrict__ W,
    const float* __restrict__ bias, float* __restrict__ C)
{
    __shared__ float As[64][68];
    __shared__ float Ws[64][68];
    const int bj = blockIdx.x, bi = blockIdx.y;
    const int t = threadIdx.x;
#pragma unroll
    for (int q2 = 0; q2 < 4; ++q2) {
        const int idx = t + 256 * q2;
        const int r = idx >> 4, c = idx & 15;
        const float4 va = *(const float4*)(A + (size_t)(bi * 64 + r) * 64 + c * 4);
        const float4 vw = *(const float4*)(W + (size_t)(bj * 64 + r) * 64 + c * 4);
        As[c*4+0][r] = va.x; As[c*4+1][r] = va.y; As[c*4+2][r] = va.z; As[c*4+3][r] = va.w;
        Ws[c*4+0][r] = vw.x; Ws[c*4+1][r] = vw.y; Ws[c*4+2][r] = vw.z; Ws[c*4+3][r] = vw.w;
    }
    __syncthreads();
    const int tx = t & 15, ty = t >> 4;
    const int i0 = ty * 4, j0 = tx * 4;
    float acc[4][4] = {};
#pragma unroll 16
    for (int k = 0; k < 64; ++k) {
        const float4 av = *(const float4*)&As[k][i0];
        const float4 wv = *(const float4*)&Ws[k][j0];
        const float* ap = (const float*)&av;
        const float* wp = (const float*)&wv;
#pragma unroll
        for (int ii = 0; ii < 4; ++ii)
#pragma unroll
            for (int jj = 0; jj < 4; ++jj)
                acc[ii][jj] = fmaf(ap[ii], wp[jj], acc[ii][jj]);
    }
    const int gj = bj * 64 + j0;
    const float4 bv = *(const float4*)(bias + gj);
#pragma unroll
    for (int ii = 0; ii < 4; ++ii) {
        const int gi = bi * 64 + i0 + ii;
        float4 o;
        o.x = fmaxf(acc[ii][0] + bv.x, 0.0f);
        o.y = fmaxf(acc[ii][1] + bv.y, 0.0f);
        o.z = fmaxf(acc[ii][2] + bv.z, 0.0f);
        o.w = fmaxf(acc[ii][3] + bv.w, 0.0f);
        *(float4*)(C + (size_t)gi * H1 + gj) = o;
    }
}

__global__ __launch_bounds__(256) void gemm2(
    const float* __restrict__ H, const float* __restrict__ W,
    const float* __restrict__ bias, float* __restrict__ O)
{
    __shared__ float Hs[64][36];
    __shared__ float Ws[64][132];
    const int bi = blockIdx.x;
    const int t = threadIdx.x;
    const int tx = t & 31, ty = t >> 5;
    const int i0 = ty * 4, j0 = tx * 4;
    float acc[4][4] = {};
    for (int kc = 0; kc < H1; kc += 64) {
#pragma unroll
        for (int q2 = 0; q2 < 2; ++q2) {
            const int idx = t + 256 * q2;
            const int r = idx >> 4, c = idx & 15;
            const float4 v = *(const float4*)(H + (size_t)(bi * 32 + r) * H1 + kc + c * 4);
            Hs[c*4+0][r] = v.x; Hs[c*4+1][r] = v.y; Hs[c*4+2][r] = v.z; Hs[c*4+3][r] = v.w;
        }
#pragma unroll
        for (int q2 = 0; q2 < 8; ++q2) {
            const int idx = t + 256 * q2;
            const int r = idx >> 4, c = idx & 15;
            const float4 v = *(const float4*)(W + (size_t)r * H1 + kc + c * 4);
            Ws[c*4+0][r] = v.x; Ws[c*4+1][r] = v.y; Ws[c*4+2][r] = v.z; Ws[c*4+3][r] = v.w;
        }
        __syncthreads();
#pragma unroll 16
        for (int k = 0; k < 64; ++k) {
            const float4 hv = *(const float4*)&Hs[k][i0];
            const float4 wv = *(const float4*)&Ws[k][j0];
            const float* hp = (const float*)&hv;
            const float* wp = (const float*)&wv;
#pragma unroll
            for (int ii = 0; ii < 4; ++ii)
#pragma unroll
                for (int jj = 0; jj < 4; ++jj)
                    acc[ii][jj] = fmaf(hp[ii], wp[jj], acc[ii][jj]);
        }
        __syncthreads();
    }
    const float4 bv = *(const float4*)(bias + j0);
#pragma unroll
    for (int ii = 0; ii < 4; ++ii) {
        const int gi = bi * 32 + i0 + ii;
        float4 o;
        o.x = fmaxf(acc[ii][0] + bv.x, 0.0f);
        o.y = fmaxf(acc[ii][1] + bv.y, 0.0f);
        o.z = fmaxf(acc[ii][2] + bv.z, 0.0f);
        o.w = fmaxf(acc[ii][3] + bv.w, 0.0f);
        *(float4*)(O + (size_t)gi * DOUT + j0) = o;
    }
}

// ============================ launch ========================================

extern "C" void kernel_launch(void* const* d_in, const int* in_sizes, int n_in,
                              void* d_out, int out_size, void* d_ws, size_t ws_size,
                              hipStream_t stream) {
    const float* x     = (const float*)d_in[0];
    const float* ea    = (const float*)d_in[1];
    const float* cg_wf = (const float*)d_in[2];
    const float* cg_bf = (const float*)d_in[3];
    const float* cg_ws = (const float*)d_in[4];
    const float* cg_bs = (const float*)d_in[5];
    const float* gcn_w = (const float*)d_in[6];
    const float* gcn_b = (const float*)d_in[7];
    const float* l3_w  = (const float*)d_in[8];
    const float* l3_b  = (const float*)d_in[9];
    const float* bn_g  = (const float*)d_in[10];
    const float* bn_b  = (const float*)d_in[11];
    const float* l4_w  = (const float*)d_in[12];
    const float* l4_b  = (const float*)d_in[13];
    const int*   ei    = (const int*)d_in[14];
    float* out = (float*)d_out;
    char* ws = (char*)d_ws;

    // bucketed-path workspace layout (8B pkw + 4B msg SoA records)
    const size_t off_pkw   = 0;
    const size_t off_msg   = off_pkw + (size_t)NB * CAP * 8;     // 142,606,336
    const size_t off_gcur  = off_msg + (size_t)NB * CAP * 4;     // + 71,303,168
    const size_t off_p1    = off_gcur + 4096;
    const size_t off_p2    = off_p1 + (size_t)NB * PWG * NODES_PB * 2 * 4;
    const size_t off_dinv  = off_p2 + (size_t)NB * PWG * NODES_PB * 4;
    const size_t off_a     = off_dinv + (size_t)N_NODES * 4;
    const size_t off_hfin  = off_a + (size_t)N_NODES * 4;
    const size_t off_h3    = off_hfin + (size_t)N_NODES * 4;
    const size_t off_w3    = off_h3 + (size_t)8192 * H1 * 4;
    const size_t off_b3    = off_w3 + (size_t)H1 * 64 * 4;
    const size_t required  = off_b3 + (size_t)H1 * 4;

    if (ws_size >= required) {
        uint2* pkw   = (uint2*)(ws + off_pkw);
        float* msgg  = (float*)(ws + off_msg);
        int*   gcur  = (int*)(ws + off_gcur);
        float* p1    = (float*)(ws + off_p1);
        float* p2    = (float*)(ws + off_p2);
        float* dinv  = (float*)(ws + off_dinv);
        float* a     = (float*)(ws + off_a);
        float* hfin  = (float*)(ws + off_hfin);
        float* h3    = (float*)(ws + off_h3);
        float* w3    = (float*)(ws + off_w3);
        float* b3    = (float*)(ws + off_b3);

        hipMemsetAsync(gcur, 0, 4096, stream);
        fold_bn<<<256, 256, 0, stream>>>(l3_w, l3_b, bn_g, bn_b, w3, b3);
        a1_bin2<<<NBLK, 256, 0, stream>>>(ei, ea, x, cg_wf, cg_bf, cg_ws, cg_bs,
                                          gcur, pkw, msgg);
        b1_accum<<<NB * PWG, 1024, 0, stream>>>(pkw, msgg, gcur, p1);
        c1_nodemid<<<N_NODES / 256, 256, 0, stream>>>(p1, x, gcn_w, dinv, a);
        b2_accum<<<NB * PWG, 1024, 0, stream>>>(pkw, gcur, a, p2);
        c2_nodefin<<<N_NODES / 256, 256, 0, stream>>>(p2, dinv, gcn_b, hfin);
        gemm1<<<dim3(16, 128), 256, 0, stream>>>(hfin, w3, b3, h3);
        gemm2<<<256, 256, 0, stream>>>(h3, l4_w, l4_b, out);
    } else {
        // fallback: device-atomic path (fits in ~42 MB)
        float* buf_msg  = (float*)(ws + 0);
        float* buf_deg  = (float*)(ws + (size_t)2097152);
        float* buf_a    = (float*)(ws + (size_t)4194304);
        float* buf_hfin = (float*)(ws + (size_t)6291456);
        float* buf_h3   = (float*)(ws + (size_t)8388608);
        float* buf_w3   = (float*)(ws + (size_t)41943040);
        float* buf_b3   = (float*)(ws + (size_t)42205184);

        hipMemsetAsync(buf_msg, 0, (size_t)N_NODES * 4, stream);
        hipMemsetAsync(buf_deg, 0, (size_t)N_NODES * 4, stream);
        fold_bn<<<256, 256, 0, stream>>>(l3_w, l3_b, bn_g, bn_b, buf_w3, buf_b3);
        edge_pass1<<<N_EDGES / 4 / 256, 256, 0, stream>>>(
            ei, ea, x, cg_wf, cg_bf, cg_ws, cg_bs, buf_msg, buf_deg);
        node_mid<<<N_NODES / 256, 256, 0, stream>>>(x, buf_msg, buf_deg, buf_a, gcn_w);
        hipMemsetAsync(buf_msg, 0, (size_t)N_NODES * 4, stream);
        edge_pass2<<<N_EDGES / 4 / 256, 256, 0, stream>>>(ei, ea, buf_a, buf_msg);
        node_fin<<<N_NODES / 256, 256, 0, stream>>>(buf_deg, buf_msg, gcn_b, buf_hfin);
        gemm1<<<dim3(16, 128), 256, 0, stream>>>(buf_hfin, buf_w3, buf_b3, buf_h3);
        gemm2<<<256, 256, 0, stream>>>(buf_h3, l4_w, l4_b, out);
    }
}

// Round 5
// 688.150 us; speedup vs baseline: 3.9486x; 1.2783x over previous
//
#include <hip/hip_runtime.h>
#include <math.h>

#define N_NODES 524288
#define N_EDGES 16777216
#define H1      1024
#define DOUT    128

// bucketed-scatter parameters
#define NB        64               // buckets
#define BSH       13               // log2(nodes per bucket)
#define NODES_PB  8192             // nodes per bucket
#define EPB       4096             // edges per a1 block
#define NBLK      (N_EDGES / EPB)  // 4096 a1 blocks
#define CAP       278528           // per-bucket record capacity (262144 avg + 16K slack)
#define PWG       8                // workgroups per bucket in accumulate phases

__device__ __forceinline__ float sigmoid_f(float v) {
    return 1.0f / (1.0f + __expf(-v));
}
__device__ __forceinline__ float softplus_f(float v) {
    return fmaxf(v, 0.0f) + log1pf(__expf(-fabsf(v)));
}

// ============================ bucketed path =================================

// ---- A1: pure binning — rank via LDS histogram, scatter {pk,w} only --------
__global__ __launch_bounds__(512) void a1_bin3(
    const int* __restrict__ ei, const float* __restrict__ ea,
    int* __restrict__ gcur,          // [NB*16] padded cursors
    uint2* __restrict__ pkw_g)
{
    __shared__ int cnt[NB];
    __shared__ int gpos[NB];
    const int c = blockIdx.x, t = threadIdx.x;

    const int vi0 = c * 1024 + t;        // 1024 int4 groups per block
    const int vi1 = vi0 + 512;
    const int4 s4a = ((const int4*)ei)[vi0];
    const int4 s4b = ((const int4*)ei)[vi1];
    const int4 d4a = ((const int4*)(ei + N_EDGES))[vi0];
    const int4 d4b = ((const int4*)(ei + N_EDGES))[vi1];
    const float4 w4a = ((const float4*)ea)[vi0];
    const float4 w4b = ((const float4*)ea)[vi1];
    int srcs[8], dsts[8];
    float ws[8];
    srcs[0]=s4a.x; srcs[1]=s4a.y; srcs[2]=s4a.z; srcs[3]=s4a.w;
    srcs[4]=s4b.x; srcs[5]=s4b.y; srcs[6]=s4b.z; srcs[7]=s4b.w;
    dsts[0]=d4a.x; dsts[1]=d4a.y; dsts[2]=d4a.z; dsts[3]=d4a.w;
    dsts[4]=d4b.x; dsts[5]=d4b.y; dsts[6]=d4b.z; dsts[7]=d4b.w;
    ws[0]=w4a.x; ws[1]=w4a.y; ws[2]=w4a.z; ws[3]=w4a.w;
    ws[4]=w4b.x; ws[5]=w4b.y; ws[6]=w4b.z; ws[7]=w4b.w;

    if (t < NB) cnt[t] = 0;
    __syncthreads();

    int rank[8];
#pragma unroll
    for (int q = 0; q < 8; ++q)
        rank[q] = atomicAdd(&cnt[dsts[q] >> BSH], 1);
    __syncthreads();

    if (t < NB) gpos[t] = atomicAdd(&gcur[t * 16], cnt[t]);
    __syncthreads();

#pragma unroll
    for (int q = 0; q < 8; ++q) {
        const int dst = dsts[q];
        const int b = dst >> BSH;
        const size_t slot = (size_t)b * CAP + gpos[b] + rank[q];
        const unsigned int pk = ((unsigned int)srcs[q] << 13) |
                                (unsigned int)(dst & (NODES_PB - 1));
        pkw_g[slot] = make_uint2(pk, __float_as_uint(ws[q]));
    }
}

// ---- B1: recompute msg, LDS-accumulate msg & deg per bucket slice ----------
__global__ __launch_bounds__(1024) void b1_accum(
    const uint2* __restrict__ pkw_g, const int* __restrict__ gcur,
    const float* __restrict__ x,
    const float* __restrict__ cg_wf, const float* __restrict__ cg_bf,
    const float* __restrict__ cg_ws, const float* __restrict__ cg_bs,
    float* __restrict__ part1)
{
    __shared__ float lm[NODES_PB];
    __shared__ float ld[NODES_PB];
    const int b = blockIdx.x / PWG, p = blockIdx.x % PWG;
    for (int i = threadIdx.x; i < NODES_PB; i += 1024) { lm[i] = 0.0f; ld[i] = 0.0f; }
    __syncthreads();
    const float wf0 = cg_wf[0], wf1 = cg_wf[1], wf2 = cg_wf[2], bf = cg_bf[0];
    const float s0c = cg_ws[0], s1c = cg_ws[1], s2c = cg_ws[2], bsc = cg_bs[0];
    const float* xb = x + (size_t)b * NODES_PB;   // bucket's dst slice
    const int tot = gcur[b * 16];
    const int per = (tot + PWG - 1) / PWG;
    const int s0 = p * per;
    const int s1 = min(tot, s0 + per);
    const size_t gb = (size_t)b * CAP;
    for (int k = s0 + (int)threadIdx.x; k < s1; k += 1024) {
        const uint2 v = pkw_g[gb + k];
        const int dl = v.x & (NODES_PB - 1);
        const int src = v.x >> 13;
        const float w = __uint_as_float(v.y);
        const float xs = x[src];
        const float xd = xb[dl];
        const float f = fmaf(wf0, xd, fmaf(wf1, xs, fmaf(wf2, w, bf)));
        const float sv = fmaf(s0c, xd, fmaf(s1c, xs, fmaf(s2c, w, bsc)));
        const float msg = sigmoid_f(f) * softplus_f(sv);
        atomicAdd(&lm[dl], msg);
        atomicAdd(&ld[dl], w);
    }
    __syncthreads();
    float* pm = part1 + (size_t)(b * PWG + p) * NODES_PB;
    float* pd = part1 + (size_t)NB * PWG * NODES_PB + (size_t)(b * PWG + p) * NODES_PB;
    for (int k = threadIdx.x; k < NODES_PB; k += 1024) { pm[k] = lm[k]; pd[k] = ld[k]; }
}

// ---- C1: combine partials + node mid (h, dinv, a) --------------------------
__global__ __launch_bounds__(256) void c1_nodemid(
    const float* __restrict__ part1, const float* __restrict__ x,
    const float* __restrict__ gcn_w,
    float* __restrict__ dinv, float* __restrict__ a)
{
    const int n = blockIdx.x * 256 + threadIdx.x;
    const int b = n >> BSH, dl = n & (NODES_PB - 1);
    const float* pm = part1 + (size_t)b * PWG * NODES_PB + dl;
    const float* pd = part1 + (size_t)NB * PWG * NODES_PB + (size_t)b * PWG * NODES_PB + dl;
    float m = 0.0f, d = 0.0f;
#pragma unroll
    for (int p = 0; p < PWG; ++p) {
        m += pm[(size_t)p * NODES_PB];
        d += pd[(size_t)p * NODES_PB];
    }
    const float h = fmaxf(x[n] + m, 0.0f);
    const float di = (d > 0.0f) ? (1.0f / sqrtf(fmaxf(d, 1e-12f))) : 0.0f;
    dinv[n] = di;
    a[n] = di * h * gcn_w[0];
}

// ---- B2: LDS-accumulate s[dst] += a[src]*w ---------------------------------
__global__ __launch_bounds__(1024) void b2_accum(
    const uint2* __restrict__ pkw_g, const int* __restrict__ gcur,
    const float* __restrict__ a, float* __restrict__ part2)
{
    __shared__ float ls[NODES_PB];
    const int b = blockIdx.x / PWG, p = blockIdx.x % PWG;
    for (int i = threadIdx.x; i < NODES_PB; i += 1024) ls[i] = 0.0f;
    __syncthreads();
    const int tot = gcur[b * 16];
    const int per = (tot + PWG - 1) / PWG;
    const int s0 = p * per;
    const int s1 = min(tot, s0 + per);
    const size_t gb = (size_t)b * CAP;
    for (int k = s0 + (int)threadIdx.x; k < s1; k += 1024) {
        const uint2 v = pkw_g[gb + k];
        atomicAdd(&ls[v.x & (NODES_PB - 1)], a[v.x >> 13] * __uint_as_float(v.y));
    }
    __syncthreads();
    float* ps = part2 + (size_t)(b * PWG + p) * NODES_PB;
    for (int k = threadIdx.x; k < NODES_PB; k += 1024) ps[k] = ls[k];
}

// ---- C2: combine partials + node fin ---------------------------------------
__global__ __launch_bounds__(256) void c2_nodefin(
    const float* __restrict__ part2, const float* __restrict__ dinv,
    const float* __restrict__ gcn_b, float* __restrict__ hfin)
{
    const int n = blockIdx.x * 256 + threadIdx.x;
    const int b = n >> BSH, dl = n & (NODES_PB - 1);
    const float* ps = part2 + (size_t)b * PWG * NODES_PB + dl;
    float s = 0.0f;
#pragma unroll
    for (int p = 0; p < PWG; ++p) s += ps[(size_t)p * NODES_PB];
    hfin[n] = fmaxf(fmaf(dinv[n], s, gcn_b[0]), 0.0f);
}

// ============================ fallback (atomic) path ========================

__global__ __launch_bounds__(256) void edge_pass1(
    const int* __restrict__ ei, const float* __restrict__ ea,
    const float* __restrict__ x,
    const float* __restrict__ cg_wf, const float* __restrict__ cg_bf,
    const float* __restrict__ cg_ws, const float* __restrict__ cg_bs,
    float* __restrict__ msg_sum, float* __restrict__ deg)
{
    const float wf0 = cg_wf[0], wf1 = cg_wf[1], wf2 = cg_wf[2], bf = cg_bf[0];
    const float s0 = cg_ws[0], s1 = cg_ws[1], s2 = cg_ws[2], bs = cg_bs[0];
    const int t = blockIdx.x * 256 + threadIdx.x;
    const int4 src4 = ((const int4*)ei)[t];
    const int4 dst4 = ((const int4*)(ei + N_EDGES))[t];
    const float4 w4 = ((const float4*)ea)[t];
    const int* sp = (const int*)&src4;
    const int* dp = (const int*)&dst4;
    const float* wp = (const float*)&w4;
#pragma unroll
    for (int q = 0; q < 4; ++q) {
        const int src = sp[q], dst = dp[q];
        const float w = wp[q];
        const float xs = x[src], xd = x[dst];
        const float f = fmaf(wf0, xd, fmaf(wf1, xs, fmaf(wf2, w, bf)));
        const float s = fmaf(s0, xd, fmaf(s1, xs, fmaf(s2, w, bs)));
        const float msg = sigmoid_f(f) * softplus_f(s);
        unsafeAtomicAdd(&msg_sum[dst], msg);
        unsafeAtomicAdd(&deg[dst], w);
    }
}

__global__ __launch_bounds__(256) void node_mid(
    const float* __restrict__ x, const float* __restrict__ msg_sum,
    float* __restrict__ deg_dinv, float* __restrict__ a,
    const float* __restrict__ gcn_w)
{
    const int i = blockIdx.x * 256 + threadIdx.x;
    const float gw = gcn_w[0];
    const float h = fmaxf(x[i] + msg_sum[i], 0.0f);
    const float d = deg_dinv[i];
    const float dinv = (d > 0.0f) ? (1.0f / sqrtf(fmaxf(d, 1e-12f))) : 0.0f;
    deg_dinv[i] = dinv;
    a[i] = dinv * h * gw;
}

__global__ __launch_bounds__(256) void edge_pass2(
    const int* __restrict__ ei, const float* __restrict__ ea,
    const float* __restrict__ a, float* __restrict__ s)
{
    const int t = blockIdx.x * 256 + threadIdx.x;
    const int4 src4 = ((const int4*)ei)[t];
    const int4 dst4 = ((const int4*)(ei + N_EDGES))[t];
    const float4 w4 = ((const float4*)ea)[t];
    const int* sp = (const int*)&src4;
    const int* dp = (const int*)&dst4;
    const float* wp = (const float*)&w4;
#pragma unroll
    for (int q = 0; q < 4; ++q)
        unsafeAtomicAdd(&s[dp[q]], a[sp[q]] * wp[q]);
}

__global__ __launch_bounds__(256) void node_fin(
    const float* __restrict__ dinv, const float* __restrict__ s,
    const float* __restrict__ gcn_b, float* __restrict__ hfin)
{
    const int i = blockIdx.x * 256 + threadIdx.x;
    hfin[i] = fmaxf(fmaf(dinv[i], s[i], gcn_b[0]), 0.0f);
}

// ============================ dense tail ====================================

__global__ __launch_bounds__(256) void fold_bn(
    const float* __restrict__ l3_w, const float* __restrict__ l3_b,
    const float* __restrict__ g, const float* __restrict__ be,
    float* __restrict__ w3f, float* __restrict__ b3f)
{
    const int idx = blockIdx.x * 256 + threadIdx.x;     // 65536
    const int j = idx >> 6, k = idx & 63;
    const float invs = 1.0f / sqrtf(1.0f + 1e-5f);
    const float sc = g[j] * invs;
    w3f[idx] = l3_w[idx] * sc;
    if (k == 0) b3f[j] = fmaf(l3_b[j], sc, be[j]);
}

__global__ __launch_bounds__(256) void gemm1(
    const float* __restrict__ A, const float* __restrict__ W,
    const float* __restrict__ bias, float* __restrict__ C)
{
    __shared__ float As[64][68];
    __shared__ float Ws[64][68];
    const int bj = blockIdx.x, bi = blockIdx.y;
    const int t = threadIdx.x;
#pragma unroll
    for (int q2 = 0; q2 < 4; ++q2) {
        const int idx = t + 256 * q2;
        const int r = idx >> 4, c = idx & 15;
        const float4 va = *(const float4*)(A + (size_t)(bi * 64 + r) * 64 + c * 4);
        const float4 vw = *(const float4*)(W + (size_t)(bj * 64 + r) * 64 + c * 4);
        As[c*4+0][r] = va.x; As[c*4+1][r] = va.y; As[c*4+2][r] = va.z; As[c*4+3][r] = va.w;
        Ws[c*4+0][r] = vw.x; Ws[c*4+1][r] = vw.y; Ws[c*4+2][r] = vw.z; Ws[c*4+3][r] = vw.w;
    }
    __syncthreads();
    const int tx = t & 15, ty = t >> 4;
    const int i0 = ty * 4, j0 = tx * 4;
    float acc[4][4] = {};
#pragma unroll 16
    for (int k = 0; k < 64; ++k) {
        const float4 av = *(const float4*)&As[k][i0];
        const float4 wv = *(const float4*)&Ws[k][j0];
        const float* ap = (const float*)&av;
        const float* wp = (const float*)&wv;
#pragma unroll
        for (int ii = 0; ii < 4; ++ii)
#pragma unroll
            for (int jj = 0; jj < 4; ++jj)
                acc[ii][jj] = fmaf(ap[ii], wp[jj], acc[ii][jj]);
    }
    const int gj = bj * 64 + j0;
    const float4 bv = *(const float4*)(bias + gj);
#pragma unroll
    for (int ii = 0; ii < 4; ++ii) {
        const int gi = bi * 64 + i0 + ii;
        float4 o;
        o.x = fmaxf(acc[ii][0] + bv.x, 0.0f);
        o.y = fmaxf(acc[ii][1] + bv.y, 0.0f);
        o.z = fmaxf(acc[ii][2] + bv.z, 0.0f);
        o.w = fmaxf(acc[ii][3] + bv.w, 0.0f);
        *(float4*)(C + (size_t)gi * H1 + gj) = o;
    }
}

__global__ __launch_bounds__(256) void gemm2(
    const float* __restrict__ H, const float* __restrict__ W,
    const float* __restrict__ bias, float* __restrict__ O)
{
    __shared__ float Hs[64][36];
    __shared__ float Ws[64][132];
    const int bi = blockIdx.x;
    const int t = threadIdx.x;
    const int tx = t & 31, ty = t >> 5;
    const int i0 = ty * 4, j0 = tx * 4;
    float acc[4][4] = {};
    for (int kc = 0; kc < H1; kc += 64) {
#pragma unroll
        for (int q2 = 0; q2 < 2; ++q2) {
            const int idx = t + 256 * q2;
            const int r = idx >> 4, c = idx & 15;
            const float4 v = *(const float4*)(H + (size_t)(bi * 32 + r) * H1 + kc + c * 4);
            Hs[c*4+0][r] = v.x; Hs[c*4+1][r] = v.y; Hs[c*4+2][r] = v.z; Hs[c*4+3][r] = v.w;
        }
#pragma unroll
        for (int q2 = 0; q2 < 8; ++q2) {
            const int idx = t + 256 * q2;
            const int r = idx >> 4, c = idx & 15;
            const float4 v = *(const float4*)(W + (size_t)r * H1 + kc + c * 4);
            Ws[c*4+0][r] = v.x; Ws[c*4+1][r] = v.y; Ws[c*4+2][r] = v.z; Ws[c*4+3][r] = v.w;
        }
        __syncthreads();
#pragma unroll 16
        for (int k = 0; k < 64; ++k) {
            const float4 hv = *(const float4*)&Hs[k][i0];
            const float4 wv = *(const float4*)&Ws[k][j0];
            const float* hp = (const float*)&hv;
            const float* wp = (const float*)&wv;
#pragma unroll
            for (int ii = 0; ii < 4; ++ii)
#pragma unroll
                for (int jj = 0; jj < 4; ++jj)
                    acc[ii][jj] = fmaf(hp[ii], wp[jj], acc[ii][jj]);
        }
        __syncthreads();
    }
    const float4 bv = *(const float4*)(bias + j0);
#pragma unroll
    for (int ii = 0; ii < 4; ++ii) {
        const int gi = bi * 32 + i0 + ii;
        float4 o;
        o.x = fmaxf(acc[ii][0] + bv.x, 0.0f);
        o.y = fmaxf(acc[ii][1] + bv.y, 0.0f);
        o.z = fmaxf(acc[ii][2] + bv.z, 0.0f);
        o.w = fmaxf(acc[ii][3] + bv.w, 0.0f);
        *(float4*)(O + (size_t)gi * DOUT + j0) = o;
    }
}

// ============================ launch ========================================

extern "C" void kernel_launch(void* const* d_in, const int* in_sizes, int n_in,
                              void* d_out, int out_size, void* d_ws, size_t ws_size,
                              hipStream_t stream) {
    const float* x     = (const float*)d_in[0];
    const float* ea    = (const float*)d_in[1];
    const float* cg_wf = (const float*)d_in[2];
    const float* cg_bf = (const float*)d_in[3];
    const float* cg_ws = (const float*)d_in[4];
    const float* cg_bs = (const float*)d_in[5];
    const float* gcn_w = (const float*)d_in[6];
    const float* gcn_b = (const float*)d_in[7];
    const float* l3_w  = (const float*)d_in[8];
    const float* l3_b  = (const float*)d_in[9];
    const float* bn_g  = (const float*)d_in[10];
    const float* bn_b  = (const float*)d_in[11];
    const float* l4_w  = (const float*)d_in[12];
    const float* l4_b  = (const float*)d_in[13];
    const int*   ei    = (const int*)d_in[14];
    float* out = (float*)d_out;
    char* ws = (char*)d_ws;

    // bucketed-path workspace layout (8B pkw records only)
    const size_t off_pkw   = 0;
    const size_t off_gcur  = off_pkw + (size_t)NB * CAP * 8;     // 142,606,336
    const size_t off_p1    = off_gcur + 4096;
    const size_t off_p2    = off_p1 + (size_t)NB * PWG * NODES_PB * 2 * 4;
    const size_t off_dinv  = off_p2 + (size_t)NB * PWG * NODES_PB * 4;
    const size_t off_a     = off_dinv + (size_t)N_NODES * 4;
    const size_t off_hfin  = off_a + (size_t)N_NODES * 4;
    const size_t off_h3    = off_hfin + (size_t)N_NODES * 4;
    const size_t off_w3    = off_h3 + (size_t)8192 * H1 * 4;
    const size_t off_b3    = off_w3 + (size_t)H1 * 64 * 4;
    const size_t required  = off_b3 + (size_t)H1 * 4;

    if (ws_size >= required) {
        uint2* pkw   = (uint2*)(ws + off_pkw);
        int*   gcur  = (int*)(ws + off_gcur);
        float* p1    = (float*)(ws + off_p1);
        float* p2    = (float*)(ws + off_p2);
        float* dinv  = (float*)(ws + off_dinv);
        float* a     = (float*)(ws + off_a);
        float* hfin  = (float*)(ws + off_hfin);
        float* h3    = (float*)(ws + off_h3);
        float* w3    = (float*)(ws + off_w3);
        float* b3    = (float*)(ws + off_b3);

        hipMemsetAsync(gcur, 0, 4096, stream);
        fold_bn<<<256, 256, 0, stream>>>(l3_w, l3_b, bn_g, bn_b, w3, b3);
        a1_bin3<<<NBLK, 512, 0, stream>>>(ei, ea, gcur, pkw);
        b1_accum<<<NB * PWG, 1024, 0, stream>>>(pkw, gcur, x,
                                                cg_wf, cg_bf, cg_ws, cg_bs, p1);
        c1_nodemid<<<N_NODES / 256, 256, 0, stream>>>(p1, x, gcn_w, dinv, a);
        b2_accum<<<NB * PWG, 1024, 0, stream>>>(pkw, gcur, a, p2);
        c2_nodefin<<<N_NODES / 256, 256, 0, stream>>>(p2, dinv, gcn_b, hfin);
        gemm1<<<dim3(16, 128), 256, 0, stream>>>(hfin, w3, b3, h3);
        gemm2<<<256, 256, 0, stream>>>(h3, l4_w, l4_b, out);
    } else {
        // fallback: device-atomic path (fits in ~42 MB)
        float* buf_msg  = (float*)(ws + 0);
        float* buf_deg  = (float*)(ws + (size_t)2097152);
        float* buf_a    = (float*)(ws + (size_t)4194304);
        float* buf_hfin = (float*)(ws + (size_t)6291456);
        float* buf_h3   = (float*)(ws + (size_t)8388608);
        float* buf_w3   = (float*)(ws + (size_t)41943040);
        float* buf_b3   = (float*)(ws + (size_t)42205184);

        hipMemsetAsync(buf_msg, 0, (size_t)N_NODES * 4, stream);
        hipMemsetAsync(buf_deg, 0, (size_t)N_NODES * 4, stream);
        fold_bn<<<256, 256, 0, stream>>>(l3_w, l3_b, bn_g, bn_b, buf_w3, buf_b3);
        edge_pass1<<<N_EDGES / 4 / 256, 256, 0, stream>>>(
            ei, ea, x, cg_wf, cg_bf, cg_ws, cg_bs, buf_msg, buf_deg);
        node_mid<<<N_NODES / 256, 256, 0, stream>>>(x, buf_msg, buf_deg, buf_a, gcn_w);
        hipMemsetAsync(buf_msg, 0, (size_t)N_NODES * 4, stream);
        edge_pass2<<<N_EDGES / 4 / 256, 256, 0, stream>>>(ei, ea, buf_a, buf_msg);
        node_fin<<<N_NODES / 256, 256, 0, stream>>>(buf_deg, buf_msg, gcn_b, buf_hfin);
        gemm1<<<dim3(16, 128), 256, 0, stream>>>(buf_hfin, buf_w3, buf_b3, buf_h3);
        gemm2<<<256, 256, 0, stream>>>(buf_h3, l4_w, l4_b, out);
    }
}

// Round 6
// 682.513 us; speedup vs baseline: 3.9813x; 1.0083x over previous
//
#include <hip/hip_runtime.h>
#include <math.h>

#define N_NODES 524288
#define N_EDGES 16777216
#define H1      1024
#define DOUT    128

// bucketed-scatter parameters
#define NB        128              // buckets
#define BSH       12               // log2(nodes per bucket)
#define NODES_PB  4096             // nodes per bucket
#define EPB       8192             // edges per a1 block
#define NBLK      (N_EDGES / EPB)  // 2048 a1 blocks
#define CAP       139264           // per-bucket record capacity (131072 avg + 8K slack, even)
#define PWG       8                // workgroups per bucket in accumulate phases

__device__ __forceinline__ float sigmoid_f(float v) {
    return 1.0f / (1.0f + __expf(-v));
}
__device__ __forceinline__ float softplus_f(float v) {
    return fmaxf(v, 0.0f) + log1pf(__expf(-fabsf(v)));
}

// ============================ bucketed path =================================

// ---- A1: pure binning — rank via LDS histogram, scatter {pk,w} -------------
// pk = (src<<12) | dst_local   (19+12 = 31 bits)
__global__ __launch_bounds__(1024) void a1_bin4(
    const int* __restrict__ ei, const float* __restrict__ ea,
    int* __restrict__ gcur,          // [NB*16] padded cursors
    uint2* __restrict__ pkw_g)
{
    __shared__ int cnt[NB];
    __shared__ int gpos[NB];
    const int c = blockIdx.x, t = threadIdx.x;

    const int vi0 = c * 2048 + t;        // 2048 int4 groups per block
    const int vi1 = vi0 + 1024;
    const int4 s4a = ((const int4*)ei)[vi0];
    const int4 s4b = ((const int4*)ei)[vi1];
    const int4 d4a = ((const int4*)(ei + N_EDGES))[vi0];
    const int4 d4b = ((const int4*)(ei + N_EDGES))[vi1];
    const float4 w4a = ((const float4*)ea)[vi0];
    const float4 w4b = ((const float4*)ea)[vi1];
    int srcs[8], dsts[8];
    float ws[8];
    srcs[0]=s4a.x; srcs[1]=s4a.y; srcs[2]=s4a.z; srcs[3]=s4a.w;
    srcs[4]=s4b.x; srcs[5]=s4b.y; srcs[6]=s4b.z; srcs[7]=s4b.w;
    dsts[0]=d4a.x; dsts[1]=d4a.y; dsts[2]=d4a.z; dsts[3]=d4a.w;
    dsts[4]=d4b.x; dsts[5]=d4b.y; dsts[6]=d4b.z; dsts[7]=d4b.w;
    ws[0]=w4a.x; ws[1]=w4a.y; ws[2]=w4a.z; ws[3]=w4a.w;
    ws[4]=w4b.x; ws[5]=w4b.y; ws[6]=w4b.z; ws[7]=w4b.w;

    if (t < NB) cnt[t] = 0;
    __syncthreads();

    int rank[8];
#pragma unroll
    for (int q = 0; q < 8; ++q)
        rank[q] = atomicAdd(&cnt[dsts[q] >> BSH], 1);
    __syncthreads();

    if (t < NB) gpos[t] = atomicAdd(&gcur[t * 16], cnt[t]);
    __syncthreads();

#pragma unroll
    for (int q = 0; q < 8; ++q) {
        const int dst = dsts[q];
        const int b = dst >> BSH;
        const size_t slot = (size_t)b * CAP + gpos[b] + rank[q];
        const unsigned int pk = ((unsigned int)srcs[q] << 12) |
                                (unsigned int)(dst & (NODES_PB - 1));
        pkw_g[slot] = make_uint2(pk, __float_as_uint(ws[q]));
    }
}

// ---- B1: recompute msg, LDS-accumulate msg & deg (paired records) ----------
__global__ __launch_bounds__(512) void b1_accum(
    const uint2* __restrict__ pkw_g, const int* __restrict__ gcur,
    const float* __restrict__ x,
    const float* __restrict__ cg_wf, const float* __restrict__ cg_bf,
    const float* __restrict__ cg_ws, const float* __restrict__ cg_bs,
    float* __restrict__ part1)
{
    __shared__ float lm[NODES_PB];
    __shared__ float ld[NODES_PB];
    const int b = blockIdx.x / PWG, p = blockIdx.x % PWG;
    for (int i = threadIdx.x; i < NODES_PB; i += 512) { lm[i] = 0.0f; ld[i] = 0.0f; }
    __syncthreads();
    const float wf0 = cg_wf[0], wf1 = cg_wf[1], wf2 = cg_wf[2], bf = cg_bf[0];
    const float s0c = cg_ws[0], s1c = cg_ws[1], s2c = cg_ws[2], bsc = cg_bs[0];
    const float* xb = x + (size_t)b * NODES_PB;   // bucket's dst slice (16 KB, L1)
    const int tot = gcur[b * 16];
    const int per = (((tot + PWG - 1) / PWG) + 1) & ~1;   // even
    const int s0 = p * per;
    const int s1 = min(tot, s0 + per);
    const uint2* base = pkw_g + (size_t)b * CAP;
    if (s1 > s0) {
        const int npair = (s1 - s0) >> 1;
        const uint4* v4 = (const uint4*)(base + s0);
#pragma unroll 2
        for (int k = threadIdx.x; k < npair; k += 512) {
            const uint4 r = v4[k];
            const int dl0 = r.x & (NODES_PB - 1), src0 = r.x >> BSH;
            const int dl1 = r.z & (NODES_PB - 1), src1 = r.z >> BSH;
            const float w0 = __uint_as_float(r.y), w1 = __uint_as_float(r.w);
            const float xs0 = x[src0], xs1 = x[src1];
            const float xd0 = xb[dl0], xd1 = xb[dl1];
            const float f0 = fmaf(wf0, xd0, fmaf(wf1, xs0, fmaf(wf2, w0, bf)));
            const float g0 = fmaf(s0c, xd0, fmaf(s1c, xs0, fmaf(s2c, w0, bsc)));
            const float f1 = fmaf(wf0, xd1, fmaf(wf1, xs1, fmaf(wf2, w1, bf)));
            const float g1 = fmaf(s0c, xd1, fmaf(s1c, xs1, fmaf(s2c, w1, bsc)));
            const float m0 = sigmoid_f(f0) * softplus_f(g0);
            const float m1 = sigmoid_f(f1) * softplus_f(g1);
            atomicAdd(&lm[dl0], m0);
            atomicAdd(&ld[dl0], w0);
            atomicAdd(&lm[dl1], m1);
            atomicAdd(&ld[dl1], w1);
        }
        // odd tail record
        for (int k = s0 + (npair << 1) + (int)threadIdx.x; k < s1; k += 512) {
            const uint2 v = base[k];
            const int dl = v.x & (NODES_PB - 1);
            const int src = v.x >> BSH;
            const float w = __uint_as_float(v.y);
            const float xs = x[src], xd = xb[dl];
            const float f = fmaf(wf0, xd, fmaf(wf1, xs, fmaf(wf2, w, bf)));
            const float g = fmaf(s0c, xd, fmaf(s1c, xs, fmaf(s2c, w, bsc)));
            atomicAdd(&lm[dl], sigmoid_f(f) * softplus_f(g));
            atomicAdd(&ld[dl], w);
        }
    }
    __syncthreads();
    float* pm = part1 + (size_t)(b * PWG + p) * NODES_PB;
    float* pd = part1 + (size_t)NB * PWG * NODES_PB + (size_t)(b * PWG + p) * NODES_PB;
    for (int k = threadIdx.x; k < NODES_PB; k += 512) { pm[k] = lm[k]; pd[k] = ld[k]; }
}

// ---- C1: combine partials + node mid (h, dinv, a) --------------------------
__global__ __launch_bounds__(256) void c1_nodemid(
    const float* __restrict__ part1, const float* __restrict__ x,
    const float* __restrict__ gcn_w,
    float* __restrict__ dinv, float* __restrict__ a)
{
    const int n = blockIdx.x * 256 + threadIdx.x;
    const int b = n >> BSH, dl = n & (NODES_PB - 1);
    const float* pm = part1 + (size_t)b * PWG * NODES_PB + dl;
    const float* pd = part1 + (size_t)NB * PWG * NODES_PB + (size_t)b * PWG * NODES_PB + dl;
    float m = 0.0f, d = 0.0f;
#pragma unroll
    for (int p = 0; p < PWG; ++p) {
        m += pm[(size_t)p * NODES_PB];
        d += pd[(size_t)p * NODES_PB];
    }
    const float h = fmaxf(x[n] + m, 0.0f);
    const float di = (d > 0.0f) ? (1.0f / sqrtf(fmaxf(d, 1e-12f))) : 0.0f;
    dinv[n] = di;
    a[n] = di * h * gcn_w[0];
}

// ---- B2: LDS-accumulate s[dst] += a[src]*w (paired records) ----------------
__global__ __launch_bounds__(512) void b2_accum(
    const uint2* __restrict__ pkw_g, const int* __restrict__ gcur,
    const float* __restrict__ a, float* __restrict__ part2)
{
    __shared__ float ls[NODES_PB];
    const int b = blockIdx.x / PWG, p = blockIdx.x % PWG;
    for (int i = threadIdx.x; i < NODES_PB; i += 512) ls[i] = 0.0f;
    __syncthreads();
    const int tot = gcur[b * 16];
    const int per = (((tot + PWG - 1) / PWG) + 1) & ~1;
    const int s0 = p * per;
    const int s1 = min(tot, s0 + per);
    const uint2* base = pkw_g + (size_t)b * CAP;
    if (s1 > s0) {
        const int npair = (s1 - s0) >> 1;
        const uint4* v4 = (const uint4*)(base + s0);
#pragma unroll 2
        for (int k = threadIdx.x; k < npair; k += 512) {
            const uint4 r = v4[k];
            const float a0 = a[r.x >> BSH];
            const float a1 = a[r.z >> BSH];
            atomicAdd(&ls[r.x & (NODES_PB - 1)], a0 * __uint_as_float(r.y));
            atomicAdd(&ls[r.z & (NODES_PB - 1)], a1 * __uint_as_float(r.w));
        }
        for (int k = s0 + (npair << 1) + (int)threadIdx.x; k < s1; k += 512) {
            const uint2 v = base[k];
            atomicAdd(&ls[v.x & (NODES_PB - 1)], a[v.x >> BSH] * __uint_as_float(v.y));
        }
    }
    __syncthreads();
    float* ps = part2 + (size_t)(b * PWG + p) * NODES_PB;
    for (int k = threadIdx.x; k < NODES_PB; k += 512) ps[k] = ls[k];
}

// ---- C2: combine partials + node fin ---------------------------------------
__global__ __launch_bounds__(256) void c2_nodefin(
    const float* __restrict__ part2, const float* __restrict__ dinv,
    const float* __restrict__ gcn_b, float* __restrict__ hfin)
{
    const int n = blockIdx.x * 256 + threadIdx.x;
    const int b = n >> BSH, dl = n & (NODES_PB - 1);
    const float* ps = part2 + (size_t)b * PWG * NODES_PB + dl;
    float s = 0.0f;
#pragma unroll
    for (int p = 0; p < PWG; ++p) s += ps[(size_t)p * NODES_PB];
    hfin[n] = fmaxf(fmaf(dinv[n], s, gcn_b[0]), 0.0f);
}

// ============================ fallback (atomic) path ========================

__global__ __launch_bounds__(256) void edge_pass1(
    const int* __restrict__ ei, const float* __restrict__ ea,
    const float* __restrict__ x,
    const float* __restrict__ cg_wf, const float* __restrict__ cg_bf,
    const float* __restrict__ cg_ws, const float* __restrict__ cg_bs,
    float* __restrict__ msg_sum, float* __restrict__ deg)
{
    const float wf0 = cg_wf[0], wf1 = cg_wf[1], wf2 = cg_wf[2], bf = cg_bf[0];
    const float s0 = cg_ws[0], s1 = cg_ws[1], s2 = cg_ws[2], bs = cg_bs[0];
    const int t = blockIdx.x * 256 + threadIdx.x;
    const int4 src4 = ((const int4*)ei)[t];
    const int4 dst4 = ((const int4*)(ei + N_EDGES))[t];
    const float4 w4 = ((const float4*)ea)[t];
    const int* sp = (const int*)&src4;
    const int* dp = (const int*)&dst4;
    const float* wp = (const float*)&w4;
#pragma unroll
    for (int q = 0; q < 4; ++q) {
        const int src = sp[q], dst = dp[q];
        const float w = wp[q];
        const float xs = x[src], xd = x[dst];
        const float f = fmaf(wf0, xd, fmaf(wf1, xs, fmaf(wf2, w, bf)));
        const float s = fmaf(s0, xd, fmaf(s1, xs, fmaf(s2, w, bs)));
        const float msg = sigmoid_f(f) * softplus_f(s);
        unsafeAtomicAdd(&msg_sum[dst], msg);
        unsafeAtomicAdd(&deg[dst], w);
    }
}

__global__ __launch_bounds__(256) void node_mid(
    const float* __restrict__ x, const float* __restrict__ msg_sum,
    float* __restrict__ deg_dinv, float* __restrict__ a,
    const float* __restrict__ gcn_w)
{
    const int i = blockIdx.x * 256 + threadIdx.x;
    const float gw = gcn_w[0];
    const float h = fmaxf(x[i] + msg_sum[i], 0.0f);
    const float d = deg_dinv[i];
    const float dinv = (d > 0.0f) ? (1.0f / sqrtf(fmaxf(d, 1e-12f))) : 0.0f;
    deg_dinv[i] = dinv;
    a[i] = dinv * h * gw;
}

__global__ __launch_bounds__(256) void edge_pass2(
    const int* __restrict__ ei, const float* __restrict__ ea,
    const float* __restrict__ a, float* __restrict__ s)
{
    const int t = blockIdx.x * 256 + threadIdx.x;
    const int4 src4 = ((const int4*)ei)[t];
    const int4 dst4 = ((const int4*)(ei + N_EDGES))[t];
    const float4 w4 = ((const float4*)ea)[t];
    const int* sp = (const int*)&src4;
    const int* dp = (const int*)&dst4;
    const float* wp = (const float*)&w4;
#pragma unroll
    for (int q = 0; q < 4; ++q)
        unsafeAtomicAdd(&s[dp[q]], a[sp[q]] * wp[q]);
}

__global__ __launch_bounds__(256) void node_fin(
    const float* __restrict__ dinv, const float* __restrict__ s,
    const float* __restrict__ gcn_b, float* __restrict__ hfin)
{
    const int i = blockIdx.x * 256 + threadIdx.x;
    hfin[i] = fmaxf(fmaf(dinv[i], s[i], gcn_b[0]), 0.0f);
}

// ============================ dense tail ====================================

__global__ __launch_bounds__(256) void fold_bn(
    const float* __restrict__ l3_w, const float* __restrict__ l3_b,
    const float* __restrict__ g, const float* __restrict__ be,
    float* __restrict__ w3f, float* __restrict__ b3f)
{
    const int idx = blockIdx.x * 256 + threadIdx.x;     // 65536
    const int j = idx >> 6, k = idx & 63;
    const float invs = 1.0f / sqrtf(1.0f + 1e-5f);
    const float sc = g[j] * invs;
    w3f[idx] = l3_w[idx] * sc;
    if (k == 0) b3f[j] = fmaf(l3_b[j], sc, be[j]);
}

__global__ __launch_bounds__(256) void gemm1(
    const float* __restrict__ A, const float* __restrict__ W,
    const float* __restrict__ bias, float* __restrict__ C)
{
    __shared__ float As[64][68];
    __shared__ float Ws[64][68];
    const int bj = blockIdx.x, bi = blockIdx.y;
    const int t = threadIdx.x;
#pragma unroll
    for (int q2 = 0; q2 < 4; ++q2) {
        const int idx = t + 256 * q2;
        const int r = idx >> 4, c = idx & 15;
        const float4 va = *(const float4*)(A + (size_t)(bi * 64 + r) * 64 + c * 4);
        const float4 vw = *(const float4*)(W + (size_t)(bj * 64 + r) * 64 + c * 4);
        As[c*4+0][r] = va.x; As[c*4+1][r] = va.y; As[c*4+2][r] = va.z; As[c*4+3][r] = va.w;
        Ws[c*4+0][r] = vw.x; Ws[c*4+1][r] = vw.y; Ws[c*4+2][r] = vw.z; Ws[c*4+3][r] = vw.w;
    }
    __syncthreads();
    const int tx = t & 15, ty = t >> 4;
    const int i0 = ty * 4, j0 = tx * 4;
    float acc[4][4] = {};
#pragma unroll 16
    for (int k = 0; k < 64; ++k) {
        const float4 av = *(const float4*)&As[k][i0];
        const float4 wv = *(const float4*)&Ws[k][j0];
        const float* ap = (const float*)&av;
        const float* wp = (const float*)&wv;
#pragma unroll
        for (int ii = 0; ii < 4; ++ii)
#pragma unroll
            for (int jj = 0; jj < 4; ++jj)
                acc[ii][jj] = fmaf(ap[ii], wp[jj], acc[ii][jj]);
    }
    const int gj = bj * 64 + j0;
    const float4 bv = *(const float4*)(bias + gj);
#pragma unroll
    for (int ii = 0; ii < 4; ++ii) {
        const int gi = bi * 64 + i0 + ii;
        float4 o;
        o.x = fmaxf(acc[ii][0] + bv.x, 0.0f);
        o.y = fmaxf(acc[ii][1] + bv.y, 0.0f);
        o.z = fmaxf(acc[ii][2] + bv.z, 0.0f);
        o.w = fmaxf(acc[ii][3] + bv.w, 0.0f);
        *(float4*)(C + (size_t)gi * H1 + gj) = o;
    }
}

__global__ __launch_bounds__(256) void gemm2(
    const float* __restrict__ H, const float* __restrict__ W,
    const float* __restrict__ bias, float* __restrict__ O)
{
    __shared__ float Hs[64][36];
    __shared__ float Ws[64][132];
    const int bi = blockIdx.x;
    const int t = threadIdx.x;
    const int tx = t & 31, ty = t >> 5;
    const int i0 = ty * 4, j0 = tx * 4;
    float acc[4][4] = {};
    for (int kc = 0; kc < H1; kc += 64) {
#pragma unroll
        for (int q2 = 0; q2 < 2; ++q2) {
            const int idx = t + 256 * q2;
            const int r = idx >> 4, c = idx & 15;
            const float4 v = *(const float4*)(H + (size_t)(bi * 32 + r) * H1 + kc + c * 4);
            Hs[c*4+0][r] = v.x; Hs[c*4+1][r] = v.y; Hs[c*4+2][r] = v.z; Hs[c*4+3][r] = v.w;
        }
#pragma unroll
        for (int q2 = 0; q2 < 8; ++q2) {
            const int idx = t + 256 * q2;
            const int r = idx >> 4, c = idx & 15;
            const float4 v = *(const float4*)(W + (size_t)r * H1 + kc + c * 4);
            Ws[c*4+0][r] = v.x; Ws[c*4+1][r] = v.y; Ws[c*4+2][r] = v.z; Ws[c*4+3][r] = v.w;
        }
        __syncthreads();
#pragma unroll 16
        for (int k = 0; k < 64; ++k) {
            const float4 hv = *(const float4*)&Hs[k][i0];
            const float4 wv = *(const float4*)&Ws[k][j0];
            const float* hp = (const float*)&hv;
            const float* wp = (const float*)&wv;
#pragma unroll
            for (int ii = 0; ii < 4; ++ii)
#pragma unroll
                for (int jj = 0; jj < 4; ++jj)
                    acc[ii][jj] = fmaf(hp[ii], wp[jj], acc[ii][jj]);
        }
        __syncthreads();
    }
    const float4 bv = *(const float4*)(bias + j0);
#pragma unroll
    for (int ii = 0; ii < 4; ++ii) {
        const int gi = bi * 32 + i0 + ii;
        float4 o;
        o.x = fmaxf(acc[ii][0] + bv.x, 0.0f);
        o.y = fmaxf(acc[ii][1] + bv.y, 0.0f);
        o.z = fmaxf(acc[ii][2] + bv.z, 0.0f);
        o.w = fmaxf(acc[ii][3] + bv.w, 0.0f);
        *(float4*)(O + (size_t)gi * DOUT + j0) = o;
    }
}

// ============================ launch ========================================

extern "C" void kernel_launch(void* const* d_in, const int* in_sizes, int n_in,
                              void* d_out, int out_size, void* d_ws, size_t ws_size,
                              hipStream_t stream) {
    const float* x     = (const float*)d_in[0];
    const float* ea    = (const float*)d_in[1];
    const float* cg_wf = (const float*)d_in[2];
    const float* cg_bf = (const float*)d_in[3];
    const float* cg_ws = (const float*)d_in[4];
    const float* cg_bs = (const float*)d_in[5];
    const float* gcn_w = (const float*)d_in[6];
    const float* gcn_b = (const float*)d_in[7];
    const float* l3_w  = (const float*)d_in[8];
    const float* l3_b  = (const float*)d_in[9];
    const float* bn_g  = (const float*)d_in[10];
    const float* bn_b  = (const float*)d_in[11];
    const float* l4_w  = (const float*)d_in[12];
    const float* l4_b  = (const float*)d_in[13];
    const int*   ei    = (const int*)d_in[14];
    float* out = (float*)d_out;
    char* ws = (char*)d_ws;

    // bucketed-path workspace layout (8B pkw records)
    const size_t off_pkw   = 0;
    const size_t off_gcur  = off_pkw + (size_t)NB * CAP * 8;     // 142,606,336
    const size_t off_p1    = off_gcur + 8192;
    const size_t off_p2    = off_p1 + (size_t)NB * PWG * NODES_PB * 2 * 4;  // 32 MB
    const size_t off_dinv  = off_p2 + (size_t)NB * PWG * NODES_PB * 4;      // 16 MB
    const size_t off_a     = off_dinv + (size_t)N_NODES * 4;
    const size_t off_hfin  = off_a + (size_t)N_NODES * 4;
    const size_t off_h3    = off_hfin + (size_t)N_NODES * 4;
    const size_t off_w3    = off_h3 + (size_t)8192 * H1 * 4;
    const size_t off_b3    = off_w3 + (size_t)H1 * 64 * 4;
    const size_t required  = off_b3 + (size_t)H1 * 4;

    if (ws_size >= required) {
        uint2* pkw   = (uint2*)(ws + off_pkw);
        int*   gcur  = (int*)(ws + off_gcur);
        float* p1    = (float*)(ws + off_p1);
        float* p2    = (float*)(ws + off_p2);
        float* dinv  = (float*)(ws + off_dinv);
        float* a     = (float*)(ws + off_a);
        float* hfin  = (float*)(ws + off_hfin);
        float* h3    = (float*)(ws + off_h3);
        float* w3    = (float*)(ws + off_w3);
        float* b3    = (float*)(ws + off_b3);

        hipMemsetAsync(gcur, 0, 8192, stream);
        fold_bn<<<256, 256, 0, stream>>>(l3_w, l3_b, bn_g, bn_b, w3, b3);
        a1_bin4<<<NBLK, 1024, 0, stream>>>(ei, ea, gcur, pkw);
        b1_accum<<<NB * PWG, 512, 0, stream>>>(pkw, gcur, x,
                                               cg_wf, cg_bf, cg_ws, cg_bs, p1);
        c1_nodemid<<<N_NODES / 256, 256, 0, stream>>>(p1, x, gcn_w, dinv, a);
        b2_accum<<<NB * PWG, 512, 0, stream>>>(pkw, gcur, a, p2);
        c2_nodefin<<<N_NODES / 256, 256, 0, stream>>>(p2, dinv, gcn_b, hfin);
        gemm1<<<dim3(16, 128), 256, 0, stream>>>(hfin, w3, b3, h3);
        gemm2<<<256, 256, 0, stream>>>(h3, l4_w, l4_b, out);
    } else {
        // fallback: device-atomic path (fits in ~42 MB)
        float* buf_msg  = (float*)(ws + 0);
        float* buf_deg  = (float*)(ws + (size_t)2097152);
        float* buf_a    = (float*)(ws + (size_t)4194304);
        float* buf_hfin = (float*)(ws + (size_t)6291456);
        float* buf_h3   = (float*)(ws + (size_t)8388608);
        float* buf_w3   = (float*)(ws + (size_t)41943040);
        float* buf_b3   = (float*)(ws + (size_t)42205184);

        hipMemsetAsync(buf_msg, 0, (size_t)N_NODES * 4, stream);
        hipMemsetAsync(buf_deg, 0, (size_t)N_NODES * 4, stream);
        fold_bn<<<256, 256, 0, stream>>>(l3_w, l3_b, bn_g, bn_b, buf_w3, buf_b3);
        edge_pass1<<<N_EDGES / 4 / 256, 256, 0, stream>>>(
            ei, ea, x, cg_wf, cg_bf, cg_ws, cg_bs, buf_msg, buf_deg);
        node_mid<<<N_NODES / 256, 256, 0, stream>>>(x, buf_msg, buf_deg, buf_a, gcn_w);
        hipMemsetAsync(buf_msg, 0, (size_t)N_NODES * 4, stream);
        edge_pass2<<<N_EDGES / 4 / 256, 256, 0, stream>>>(ei, ea, buf_a, buf_msg);
        node_fin<<<N_NODES / 256, 256, 0, stream>>>(buf_deg, buf_msg, gcn_b, buf_hfin);
        gemm1<<<dim3(16, 128), 256, 0, stream>>>(buf_hfin, buf_w3, buf_b3, buf_h3);
        gemm2<<<256, 256, 0, stream>>>(buf_h3, l4_w, l4_b, out);
    }
}